// Round 3
// baseline (6628.686 us; speedup 1.0000x reference)
//
#include <hip/hip_runtime.h>
#include <cstdint>
#include <cstddef>

#define B_    256
#define Q_    512
#define D_    32
#define H_    192
#define HID_  384
#define INCH_ 96
#define M_    (B_*Q_)    // 131072
#define WOUT_ 64
#define PI_F  3.14159265358979323846f

__device__ __forceinline__ float sigm(float x){ return 1.f/(1.f+expf(-x)); }
__device__ __forceinline__ float gelu_exact(float x){ return 0.5f*x*(1.f+erff(x*0.7071067811865475f)); }

// ---------------- features: [x, dy, ddy]  (chunk of nrows rows) ----------------
__global__ void feats_kernel(const float* __restrict__ x, float* __restrict__ feats, int nrows){
  int idx = blockIdx.x*256 + threadIdx.x;
  if (idx >= nrows*32) return;
  int d  = idx & 31;
  int bt = idx >> 5;
  int t  = bt & 511;
  const float* xr = x + (size_t)bt*D_;
  float xc  = xr[d];
  float xm1 = (t>0) ? xr[d - D_]   : 0.f;
  float xm2 = (t>1) ? xr[d - 2*D_] : 0.f;
  float dy   = (t>0) ? xc - xm1   : 0.f;
  float dym1 = (t>1) ? xm1 - xm2  : 0.f;
  float ddy  = (t>0) ? dy - dym1  : 0.f;
  float* fr = feats + (size_t)bt*INCH_;
  fr[d] = xc; fr[D_+d] = dy; fr[2*D_+d] = ddy;
}

// ---------------- generic 128x128x8 fp32 tiled GEMM ----------------
// C[m,o] = sum_c A[m,c]*W[o,c]  (+epilogue).  A row-major (Mc,K), W row-major (N,K).
// MODE 0: out = acc + bias
// MODE 1: out = gelu(acc + bias)
// MODE 2: A with affine (a*scale[b_local,c] + grnb[c]); out in-place: C += acc + bias
template<int MODE>
__global__ __launch_bounds__(256,2) void gemm128(
    const float* __restrict__ Af,
    const float* __restrict__ W,  const float* __restrict__ bias,
    float* __restrict__ Cf,
    const float* __restrict__ scale, const float* __restrict__ grnb,
    int N, int K)
{
  __shared__ float As[8][128];
  __shared__ float Bs[8][128];
  const int tid = threadIdx.x;
  const int bm = blockIdx.x * 128;
  const int bn = blockIdx.y * 128;
  const int tx = tid & 15, ty = tid >> 4;
  const int lrow = tid >> 1, lk = (tid & 1) * 4;

  float acc[8][8];
  for (int i=0;i<8;i++)
    for (int j=0;j<8;j++) acc[i][j]=0.f;

  const float* srow = (MODE==2) ? (scale + (size_t)(bm >> 9) * HID_) : nullptr;
  const bool brow_ok = (bn + lrow) < N;

  for (int k0 = 0; k0 < K; k0 += 8){
    float4 av = *(const float4*)(Af + (size_t)(bm+lrow)*K + k0 + lk);
    if (MODE==2){
      int c = k0 + lk;
      float4 sc = *(const float4*)(srow + c);
      float4 gb = *(const float4*)(grnb + c);
      av.x = av.x*sc.x + gb.x; av.y = av.y*sc.y + gb.y;
      av.z = av.z*sc.z + gb.z; av.w = av.w*sc.w + gb.w;
    }
    float4 bv = make_float4(0.f,0.f,0.f,0.f);
    if (brow_ok) bv = *(const float4*)(W + (size_t)(bn+lrow)*K + k0 + lk);

    As[lk+0][lrow]=av.x; As[lk+1][lrow]=av.y; As[lk+2][lrow]=av.z; As[lk+3][lrow]=av.w;
    Bs[lk+0][lrow]=bv.x; Bs[lk+1][lrow]=bv.y; Bs[lk+2][lrow]=bv.z; Bs[lk+3][lrow]=bv.w;
    __syncthreads();
    #pragma unroll
    for (int kk=0;kk<8;kk++){
      float a[8], b[8];
      *(float4*)&a[0] = *(const float4*)&As[kk][ty*8];
      *(float4*)&a[4] = *(const float4*)&As[kk][ty*8+4];
      *(float4*)&b[0] = *(const float4*)&Bs[kk][tx*4];
      *(float4*)&b[4] = *(const float4*)&Bs[kk][64+tx*4];
      #pragma unroll
      for (int i=0;i<8;i++)
        #pragma unroll
        for (int j=0;j<8;j++) acc[i][j] += a[i]*b[j];
    }
    __syncthreads();
  }

  const bool ok0 = (bn + 64)  <= N;
  const bool ok1 = (bn + 128) <= N;
  const int o0 = bn + tx*4, o1 = bn + 64 + tx*4;
  float4 bias0 = make_float4(0,0,0,0), bias1 = make_float4(0,0,0,0);
  if (ok0) bias0 = *(const float4*)(bias + o0);
  if (ok1) bias1 = *(const float4*)(bias + o1);

  #pragma unroll
  for (int i=0;i<8;i++){
    int m = bm + ty*8 + i;
    if (MODE==0){
      if (ok0){
        float4 v; v.x=acc[i][0]+bias0.x; v.y=acc[i][1]+bias0.y; v.z=acc[i][2]+bias0.z; v.w=acc[i][3]+bias0.w;
        *(float4*)(Cf + (size_t)m*N + o0) = v;
      }
      if (ok1){
        float4 v; v.x=acc[i][4]+bias1.x; v.y=acc[i][5]+bias1.y; v.z=acc[i][6]+bias1.z; v.w=acc[i][7]+bias1.w;
        *(float4*)(Cf + (size_t)m*N + o1) = v;
      }
    } else if (MODE==1){
      if (ok0){
        float4 v;
        v.x = gelu_exact(acc[i][0]+bias0.x); v.y = gelu_exact(acc[i][1]+bias0.y);
        v.z = gelu_exact(acc[i][2]+bias0.z); v.w = gelu_exact(acc[i][3]+bias0.w);
        *(float4*)(Cf + (size_t)m*N + o0) = v;
      }
      if (ok1){
        float4 v;
        v.x = gelu_exact(acc[i][4]+bias1.x); v.y = gelu_exact(acc[i][5]+bias1.y);
        v.z = gelu_exact(acc[i][6]+bias1.z); v.w = gelu_exact(acc[i][7]+bias1.w);
        *(float4*)(Cf + (size_t)m*N + o1) = v;
      }
    } else {
      if (ok0){
        float4 old = *(const float4*)(Cf + (size_t)m*N + o0);
        float4 v; v.x=old.x+acc[i][0]+bias0.x; v.y=old.y+acc[i][1]+bias0.y; v.z=old.z+acc[i][2]+bias0.z; v.w=old.w+acc[i][3]+bias0.w;
        *(float4*)(Cf + (size_t)m*N + o0) = v;
      }
      if (ok1){
        float4 old = *(const float4*)(Cf + (size_t)m*N + o1);
        float4 v; v.x=old.x+acc[i][4]+bias1.x; v.y=old.y+acc[i][5]+bias1.y; v.z=old.z+acc[i][6]+bias1.z; v.w=old.w+acc[i][7]+bias1.w;
        *(float4*)(Cf + (size_t)m*N + o1) = v;
      }
    }
  }
}

// ---------------- depthwise conv (k=9, edge pad) + LayerNorm over channels ----------------
__global__ __launch_bounds__(192) void dwconv_ln_kernel(
  const float* __restrict__ h, const float* __restrict__ dww, const float* __restrict__ dwb,
  const float* __restrict__ lnw, const float* __restrict__ lnb, float* __restrict__ yln)
{
  __shared__ float rs_[192], rq_[192], st[2];
  const int c  = threadIdx.x;
  const int bt = blockIdx.x;
  const int t  = bt & 511;
  const float* hb = h + (size_t)(bt & ~511) * H_;
  float acc = dwb[c];
  #pragma unroll
  for (int k=0;k<9;k++){
    int tt = t + k - 4; tt = tt < 0 ? 0 : (tt > 511 ? 511 : tt);
    acc += dww[c*9+k] * hb[(size_t)tt*H_ + c];
  }
  rs_[c] = acc; rq_[c] = acc*acc;
  __syncthreads();
  if (c < 64){
    float s = rs_[c]+rs_[c+64]+rs_[c+128];
    float q = rq_[c]+rq_[c+64]+rq_[c+128];
    #pragma unroll
    for (int off=32; off>0; off>>=1){ s += __shfl_down(s,off); q += __shfl_down(q,off); }
    if (c==0){ st[0]=s; st[1]=q; }
  }
  __syncthreads();
  float mean = st[0]*(1.f/H_);
  float var  = st[1]*(1.f/H_) - mean*mean;
  float r = rsqrtf(var + 1e-5f);
  yln[(size_t)bt*H_ + c] = (acc-mean)*r*lnw[c] + lnb[c];
}

// ---------------- output LayerNorm (+ save last-timestep row to hlast) ----------------
__global__ __launch_bounds__(192) void out_ln_kernel(
  const float* __restrict__ h, const float* __restrict__ lnw, const float* __restrict__ lnb,
  float* __restrict__ o, float* __restrict__ hlast, int b0)
{
  __shared__ float rs_[192], rq_[192], st[2];
  const int c  = threadIdx.x;
  const int bt = blockIdx.x;
  float v = h[(size_t)bt*H_ + c];
  rs_[c]=v; rq_[c]=v*v;
  __syncthreads();
  if (c < 64){
    float s = rs_[c]+rs_[c+64]+rs_[c+128];
    float q = rq_[c]+rq_[c+64]+rq_[c+128];
    #pragma unroll
    for (int off=32; off>0; off>>=1){ s += __shfl_down(s,off); q += __shfl_down(q,off); }
    if (c==0){ st[0]=s; st[1]=q; }
  }
  __syncthreads();
  float mean = st[0]*(1.f/H_);
  float var  = st[1]*(1.f/H_) - mean*mean;
  float r = rsqrtf(var + 1e-5f);
  float res = (v-mean)*r*lnw[c] + lnb[c];
  o[(size_t)bt*H_ + c] = res;
  if ((bt & 511) == 511) hlast[(size_t)(b0 + (bt>>9))*H_ + c] = res;
}

// ---------------- GRN stats: scale[b,c] = 1 + g[c]*gx/(mean_c(gx)+1e-6) ----------------
__global__ __launch_bounds__(384) void grn_stats_kernel(
  const float* __restrict__ y1, const float* __restrict__ grn_g, float* __restrict__ scale)
{
  __shared__ float r[384];
  const int c = threadIdx.x;
  const int b = blockIdx.x;
  const float* p = y1 + (size_t)b*Q_*HID_ + c;
  float s = 0.f;
  #pragma unroll 4
  for (int t=0;t<Q_;t++){ float v = p[(size_t)t*HID_]; s += v*v; }
  float gx = sqrtf(s);
  r[c] = gx;
  __syncthreads();
  if (c < 64){
    float v = r[c]+r[c+64]+r[c+128]+r[c+192]+r[c+256]+r[c+320];
    #pragma unroll
    for (int off=32; off>0; off>>=1) v += __shfl_down(v,off);
    if (c==0) r[0]=v;
  }
  __syncthreads();
  float mean = r[0]*(1.f/HID_);
  scale[(size_t)b*HID_ + c] = 1.f + grn_g[c]*gx/(mean + 1e-6f);
}

// ---------------- pack fc_rp / fc_gain into padded (64,192) W ----------------
__global__ void pack_w_kernel(const float* __restrict__ frw, const float* __restrict__ frb,
                              const float* __restrict__ fgw, const float* __restrict__ fgb,
                              float* __restrict__ w_pad, float* __restrict__ b_pad)
{
  int idx = blockIdx.x*256 + threadIdx.x;
  if (idx >= 64*192) return;
  int o = idx / 192, k = idx % 192;
  float v = 0.f;
  if (o < 2) v = frw[o*192+k]; else if (o < 34) v = fgw[(o-2)*192+k];
  w_pad[idx] = v;
  if (k == 0){
    float bv = 0.f;
    if (o < 2) bv = frb[o]; else if (o < 34) bv = fgb[o-2];
    b_pad[o] = bv;
  }
}

// ---------------- sequential Kalman scan (reads raw logits, stride 64) ----------------
__global__ __launch_bounds__(64) void kalman_scan_kernel(
  const float* __restrict__ x_c, const float* __restrict__ raw, float* __restrict__ xpost,
  int b0, int Bc)
{
  const int lane = threadIdx.x;
  const int bl = blockIdx.x*4 + (lane>>4);   // chunk-local batch
  if (bl >= Bc) return;
  const int m = lane & 15;
  const float* xb = x_c + (size_t)bl*Q_*D_;
  const float* rb = raw + (size_t)bl*Q_*64;
  float re = xb[m], im = xb[16+m];
  for (int t=0;t<Q_;t++){
    const float* r = rb + (size_t)t*64;
    float rho = 1.25f*sigm(r[0]);
    float phi = PI_F*tanhf(r[1]);
    float rc = rho*cosf(phi), rs = rho*sinf(phi);
    float g0 = sigm(r[2+m]), g1 = sigm(r[18+m]);
    float y0 = xb[(size_t)t*D_ + m], y1v = xb[(size_t)t*D_ + 16 + m];
    float pr  = rc*re - rs*im;
    float pim = rs*re + rc*im;
    re = pr  + g0*(y0  - pr);
    im = pim + g1*(y1v - pim);
  }
  xpost[(b0+bl)*D_ + m] = re;
  xpost[(b0+bl)*D_ + 16 + m] = im;
}

// ---------------- transpose rollout weights for coalesced GEMV ----------------
__global__ void prep_rollout_kernel(const float* __restrict__ riw, const float* __restrict__ wih,
                                    const float* __restrict__ whh,
                                    float* __restrict__ wT1, float* __restrict__ wTih, float* __restrict__ wTwhh)
{
  int idx = blockIdx.x*256 + threadIdx.x;
  if (idx < 224*192){
    int o = idx % 192, k = idx / 192;
    wT1[idx] = riw[o*224 + k];
    return;
  }
  idx -= 224*192;
  if (idx < 192*576){
    int o = idx % 576, k = idx / 576;
    wTih[idx] = wih[o*192 + k];
    return;
  }
  idx -= 192*576;
  if (idx < 192*576){
    int o = idx % 576, k = idx / 576;
    wTwhh[idx] = whh[o*192 + k];
  }
}

// ---------------- GRU rollout: 1 batch per block, 64 sequential steps ----------------
__global__ __launch_bounds__(192) void rollout_kernel(
  const float* __restrict__ hlast, const float* __restrict__ xpost,
  const float* __restrict__ wT1,  const float* __restrict__ rib_,
  const float* __restrict__ wTih, const float* __restrict__ wTwhh,
  const float* __restrict__ bih,  const float* __restrict__ bhh,
  const float* __restrict__ lnw,  const float* __restrict__ lnb,
  const float* __restrict__ frw,  const float* __restrict__ frb,
  float* __restrict__ out)
{
  const int tid = threadIdx.x;
  const int b = blockIdx.x;
  __shared__ float h[192], x[192], c[32];
  __shared__ float red1[192], red2[192];
  __shared__ float stA[2], stB[2];

  h[tid] = hlast[(size_t)b*H_ + tid];
  if (tid < 32) c[tid] = xpost[b*D_ + tid];
  const float w_ln = lnw[tid], b_ln = lnb[tid];
  const float w_r0 = frw[tid], w_r1 = frw[192+tid];
  const float fb0 = frb[0], fb1 = frb[1];
  const float bi0 = bih[tid], bi1 = bih[192+tid], bi2 = bih[384+tid];
  const float bh0 = bhh[tid], bh1 = bhh[192+tid], bh2 = bhh[384+tid];
  const float rib = rib_[tid];
  __syncthreads();

  for (int s=0; s<WOUT_; s++){
    // x = tanh([h_r, curr] @ W1^T + b1)
    float a = rib;
    for (int k=0;k<192;k++) a += wT1[k*192+tid]*h[k];
    #pragma unroll
    for (int k=0;k<32;k++) a += wT1[(192+k)*192+tid]*c[k];
    x[tid] = tanhf(a);
    __syncthreads();

    // gi = x@Wih^T + bih ; gh = h_r@Whh^T + bhh
    float p0=bi0, p1=bi1, p2=bi2;
    float q0=bh0, q1=bh1, q2=bh2;
    for (int k=0;k<192;k++){
      float xv = x[k], hv = h[k];
      const float* wi = wTih  + k*576 + tid;
      const float* wh = wTwhh + k*576 + tid;
      p0 += wi[0]*xv;   p1 += wi[192]*xv; p2 += wi[384]*xv;
      q0 += wh[0]*hv;   q1 += wh[192]*hv; q2 += wh[384]*hv;
    }
    float hold = h[tid];
    float rg = sigm(p0+q0), z = sigm(p1+q1);
    float n  = tanhf(p2 + rg*q2);
    float pre = (1.f - z)*n + z*hold;

    // LN over 192
    red1[tid]=pre; red2[tid]=pre*pre;
    __syncthreads();
    if (tid < 64){
      float s0=red1[tid]+red1[tid+64]+red1[tid+128];
      float q0r=red2[tid]+red2[tid+64]+red2[tid+128];
      #pragma unroll
      for (int off=32; off>0; off>>=1){ s0 += __shfl_down(s0,off); q0r += __shfl_down(q0r,off); }
      if (tid==0){ stA[0]=s0; stA[1]=q0r; }
    }
    __syncthreads();
    const float inv = 1.f/192.f;
    float mu = stA[0]*inv, var = stA[1]*inv - mu*mu;
    float hn = (pre-mu)*rsqrtf(var+1e-5f)*w_ln + b_ln;
    h[tid] = hn;

    // rho/phi dots
    red1[tid]=hn*w_r0; red2[tid]=hn*w_r1;
    __syncthreads();
    if (tid < 64){
      float s0=red1[tid]+red1[tid+64]+red1[tid+128];
      float q0r=red2[tid]+red2[tid+64]+red2[tid+128];
      #pragma unroll
      for (int off=32; off>0; off>>=1){ s0 += __shfl_down(s0,off); q0r += __shfl_down(q0r,off); }
      if (tid==0){ stB[0]=s0; stB[1]=q0r; }
    }
    __syncthreads();
    if (tid < 16){
      float rho = 1.25f*sigm(stB[0]+fb0);
      float phi = PI_F*tanhf(stB[1]+fb1);
      float rc = rho*cosf(phi), rs = rho*sinf(phi);
      float re = c[tid], im = c[tid+16];
      float nre = rc*re - rs*im;
      float nim = rs*re + rc*im;
      c[tid] = nre; c[tid+16] = nim;
      float* ob = out + ((size_t)b*WOUT_ + s)*D_;
      ob[tid] = nre; ob[tid+16] = nim;
    }
    __syncthreads();
  }
}

// ---------------- host launch ----------------
extern "C" void kernel_launch(void* const* d_in, const int* in_sizes, int n_in,
                              void* d_out, int out_size, void* d_ws, size_t ws_size,
                              hipStream_t stream)
{
  const float* x_in     = (const float*)d_in[0];
  const float* inp_w    = (const float*)d_in[1];
  const float* inp_b    = (const float*)d_in[2];
  const float* b_dw_w   = (const float*)d_in[3];
  const float* b_dw_b   = (const float*)d_in[4];
  const float* b_ln_w   = (const float*)d_in[5];
  const float* b_ln_b   = (const float*)d_in[6];
  const float* b_pw1_w  = (const float*)d_in[7];
  const float* b_pw1_b  = (const float*)d_in[8];
  const float* b_grn_g  = (const float*)d_in[9];
  const float* b_grn_b  = (const float*)d_in[10];
  const float* b_pw2_w  = (const float*)d_in[11];
  const float* b_pw2_b  = (const float*)d_in[12];
  const float* out_ln_w = (const float*)d_in[13];
  const float* out_ln_b = (const float*)d_in[14];
  const float* fc_rp_w  = (const float*)d_in[15];
  const float* fc_rp_b  = (const float*)d_in[16];
  const float* fc_gain_w= (const float*)d_in[17];
  const float* fc_gain_b= (const float*)d_in[18];
  const float* roll_in_w= (const float*)d_in[19];
  const float* roll_in_b= (const float*)d_in[20];
  const float* gru_wih  = (const float*)d_in[21];
  const float* gru_whh  = (const float*)d_in[22];
  const float* gru_bih  = (const float*)d_in[23];
  const float* gru_bhh  = (const float*)d_in[24];
  const float* roll_ln_w= (const float*)d_in[25];
  const float* roll_ln_b= (const float*)d_in[26];
  const float* fc_rp_r_w= (const float*)d_in[27];
  const float* fc_rp_r_b= (const float*)d_in[28];
  float* out = (float*)d_out;

  // ---- adaptive chunking ----
  // per-row floats: h(192) + yln(192) + mid(384, holds feats then fp32 y1) + rpraw(64) = 832
  // fixed tail (exact): 98304+12288+64+8192+49152+43008+110592+110592 = 432192; +margin
  const size_t SMAL_FLOATS = 432192 + 4096;
  size_t ws_floats = ws_size / 4;
  int nchunk = 256;
  const int cand[9] = {1,2,4,8,16,32,64,128,256};
  for (int ci=0; ci<9; ci++){
    size_t Mc_try = (size_t)M_ / cand[ci];
    if (Mc_try*832 + SMAL_FLOATS <= ws_floats){ nchunk = cand[ci]; break; }
  }
  const int    Bc = B_ / nchunk;
  const size_t Mc = (size_t)Bc * Q_;

  float* ws    = (float*)d_ws;
  float* h_c   = ws;                     // Mc*192
  float* yln_c = h_c   + Mc*192;         // Mc*192 (also h_seq per chunk)
  float* mid_c = yln_c + Mc*192;         // Mc*384: feats (Mc*96) then y1 fp32 (Mc*384)
  float* rpraw = mid_c + Mc*384;         // Mc*64
  float* smal  = rpraw + Mc*64;

  float* feats_c = mid_c;
  float* y1_c    = mid_c;

  float* scaleB = smal;                  // Bc*384 (reserve 98304)
  float* w_pad  = smal + 98304;          // 64*192
  float* b_pad  = w_pad + 12288;         // 64
  float* xpost  = b_pad + 64;            // B_*32
  float* hlast  = xpost + 8192;          // B_*192
  float* wT1    = hlast + 49152;         // 224*192
  float* wTih   = wT1 + 43008;           // 192*576
  float* wTwhh  = wTih + 110592;         // 192*576

  // one-time weight prep
  pack_w_kernel<<<(64*192+255)/256, 256, 0, stream>>>(fc_rp_w, fc_rp_b, fc_gain_w, fc_gain_b, w_pad, b_pad);
  prep_rollout_kernel<<<(264192+255)/256, 256, 0, stream>>>(roll_in_w, gru_wih, gru_whh, wT1, wTih, wTwhh);

  const int gemm_mx = (int)(Mc/128);
  for (int ch=0; ch<nchunk; ch++){
    const float* x_c = x_in + (size_t)ch*Mc*D_;
    // 1. features + input projection
    feats_kernel<<<(int)((Mc*32+255)/256), 256, 0, stream>>>(x_c, feats_c, (int)Mc);
    gemm128<0><<<dim3(gemm_mx, 2), 256, 0, stream>>>(feats_c, inp_w, inp_b,
                                                     h_c, nullptr, nullptr, H_, INCH_);
    // 2. ConvNeXt blocks
    for (int blk = 0; blk < 2; blk++){
      const float* dww = b_dw_w + blk*H_*9;     const float* dwb = b_dw_b + blk*H_;
      const float* lnw = b_ln_w + blk*H_;       const float* lnb = b_ln_b + blk*H_;
      const float* p1w = b_pw1_w + blk*HID_*H_; const float* p1b = b_pw1_b + blk*HID_;
      const float* gg  = b_grn_g + blk*HID_;    const float* gb  = b_grn_b + blk*HID_;
      const float* p2w = b_pw2_w + blk*H_*HID_; const float* p2b = b_pw2_b + blk*H_;
      dwconv_ln_kernel<<<(int)Mc, 192, 0, stream>>>(h_c, dww, dwb, lnw, lnb, yln_c);
      gemm128<1><<<dim3(gemm_mx, 3), 256, 0, stream>>>(yln_c, p1w, p1b,
                                                       y1_c, nullptr, nullptr, HID_, H_);
      grn_stats_kernel<<<Bc, 384, 0, stream>>>(y1_c, gg, scaleB);
      gemm128<2><<<dim3(gemm_mx, 2), 256, 0, stream>>>(y1_c, p2w, p2b,
                                                       h_c, scaleB, gb, H_, HID_);
    }
    // 3. output LN -> h_seq (reuse yln_c), save last-t rows
    out_ln_kernel<<<(int)Mc, 192, 0, stream>>>(h_c, out_ln_w, out_ln_b, yln_c, hlast, ch*Bc);
    // 4. Kalman projection + sequential scan
    gemm128<0><<<dim3(gemm_mx, 1), 256, 0, stream>>>(yln_c, w_pad, b_pad,
                                                     rpraw, nullptr, nullptr, 64, H_);
    kalman_scan_kernel<<<(Bc+3)/4, 64, 0, stream>>>(x_c, rpraw, xpost, ch*Bc, Bc);
  }
  // 5. GRU rollout (all batches)
  rollout_kernel<<<B_, 192, 0, stream>>>(hlast, xpost, wT1, roll_in_b, wTih, wTwhh,
                                         gru_bih, gru_bhh, roll_ln_w, roll_ln_b,
                                         fc_rp_r_w, fc_rp_r_b, out);
  (void)in_sizes; (void)n_in; (void)out_size; (void)ws_size;
}

// Round 4
// 4538.734 us; speedup vs baseline: 1.4605x; 1.4605x over previous
//
#include <hip/hip_runtime.h>
#include <cstdint>
#include <cstddef>

#define B_    256
#define Q_    512
#define D_    32
#define H_    192
#define HID_  384
#define INCH_ 96
#define M_    (B_*Q_)    // 131072
#define WOUT_ 64
#define BPB   4          // batches per rollout block
#define PI_F  3.14159265358979323846f

__device__ __forceinline__ float sigm(float x){ return 1.f/(1.f+expf(-x)); }
__device__ __forceinline__ float gelu_exact(float x){ return 0.5f*x*(1.f+erff(x*0.7071067811865475f)); }

// ---------------- features: [x, dy, ddy]  (chunk of nrows rows) ----------------
__global__ void feats_kernel(const float* __restrict__ x, float* __restrict__ feats, int nrows){
  int idx = blockIdx.x*256 + threadIdx.x;
  if (idx >= nrows*32) return;
  int d  = idx & 31;
  int bt = idx >> 5;
  int t  = bt & 511;
  const float* xr = x + (size_t)bt*D_;
  float xc  = xr[d];
  float xm1 = (t>0) ? xr[d - D_]   : 0.f;
  float xm2 = (t>1) ? xr[d - 2*D_] : 0.f;
  float dy   = (t>0) ? xc - xm1   : 0.f;
  float dym1 = (t>1) ? xm1 - xm2  : 0.f;
  float ddy  = (t>0) ? dy - dym1  : 0.f;
  float* fr = feats + (size_t)bt*INCH_;
  fr[d] = xc; fr[D_+d] = dy; fr[2*D_+d] = ddy;
}

// ---------------- 64x128x8 fp32 tiled GEMM (better grid coverage) ----------------
// C[m,o] = sum_c A[m,c]*W[o,c] (+epilogue). A (Mc,K) row-major, W (N,K) row-major.
// MODE 0: out = acc + bias ; MODE 1: out = gelu(acc+bias) ; MODE 2: A affine, C += acc+bias
template<int MODE>
__global__ __launch_bounds__(256,4) void gemm64(
    const float* __restrict__ Af,
    const float* __restrict__ W,  const float* __restrict__ bias,
    float* __restrict__ Cf,
    const float* __restrict__ scale, const float* __restrict__ grnb,
    int N, int K)
{
  __shared__ float As[8][64];
  __shared__ float Bs[8][128];
  const int tid = threadIdx.x;
  const int bm = blockIdx.x * 64;
  const int bn = blockIdx.y * 128;
  const int tx = tid & 15, ty = tid >> 4;        // ty: 16 groups of 4 rows; tx: 8 cols (4+4)
  const int brow = tid >> 1, lk = (tid & 1) * 4; // B stage: rows 0..127
  const int arow = (tid & 127) >> 1;             // A stage (tid<128): rows 0..63

  float acc[4][8];
  #pragma unroll
  for (int i=0;i<4;i++)
    #pragma unroll
    for (int j=0;j<8;j++) acc[i][j]=0.f;

  const float* srow = (MODE==2) ? (scale + (size_t)(bm >> 9) * HID_) : nullptr;
  const bool brow_ok = (bn + brow) < N;
  const bool aload   = tid < 128;

  for (int k0 = 0; k0 < K; k0 += 8){
    float4 av = make_float4(0.f,0.f,0.f,0.f);
    if (aload){
      av = *(const float4*)(Af + (size_t)(bm+arow)*K + k0 + lk);
      if (MODE==2){
        int c = k0 + lk;
        float4 sc = *(const float4*)(srow + c);
        float4 gb = *(const float4*)(grnb + c);
        av.x = av.x*sc.x + gb.x; av.y = av.y*sc.y + gb.y;
        av.z = av.z*sc.z + gb.z; av.w = av.w*sc.w + gb.w;
      }
    }
    float4 bv = make_float4(0.f,0.f,0.f,0.f);
    if (brow_ok) bv = *(const float4*)(W + (size_t)(bn+brow)*K + k0 + lk);

    if (aload){
      As[lk+0][arow]=av.x; As[lk+1][arow]=av.y; As[lk+2][arow]=av.z; As[lk+3][arow]=av.w;
    }
    Bs[lk+0][brow]=bv.x; Bs[lk+1][brow]=bv.y; Bs[lk+2][brow]=bv.z; Bs[lk+3][brow]=bv.w;
    __syncthreads();
    #pragma unroll
    for (int kk=0;kk<8;kk++){
      float a[4], b[8];
      *(float4*)&a[0] = *(const float4*)&As[kk][ty*4];
      *(float4*)&b[0] = *(const float4*)&Bs[kk][tx*4];
      *(float4*)&b[4] = *(const float4*)&Bs[kk][64+tx*4];
      #pragma unroll
      for (int i=0;i<4;i++)
        #pragma unroll
        for (int j=0;j<8;j++) acc[i][j] += a[i]*b[j];
    }
    __syncthreads();
  }

  const bool ok0 = (bn + 64)  <= N;
  const bool ok1 = (bn + 128) <= N;
  const int o0 = bn + tx*4, o1 = bn + 64 + tx*4;
  float4 bias0 = make_float4(0,0,0,0), bias1 = make_float4(0,0,0,0);
  if (ok0) bias0 = *(const float4*)(bias + o0);
  if (ok1) bias1 = *(const float4*)(bias + o1);

  #pragma unroll
  for (int i=0;i<4;i++){
    int m = bm + ty*4 + i;
    if (MODE==0){
      if (ok0){
        float4 v; v.x=acc[i][0]+bias0.x; v.y=acc[i][1]+bias0.y; v.z=acc[i][2]+bias0.z; v.w=acc[i][3]+bias0.w;
        *(float4*)(Cf + (size_t)m*N + o0) = v;
      }
      if (ok1){
        float4 v; v.x=acc[i][4]+bias1.x; v.y=acc[i][5]+bias1.y; v.z=acc[i][6]+bias1.z; v.w=acc[i][7]+bias1.w;
        *(float4*)(Cf + (size_t)m*N + o1) = v;
      }
    } else if (MODE==1){
      if (ok0){
        float4 v;
        v.x = gelu_exact(acc[i][0]+bias0.x); v.y = gelu_exact(acc[i][1]+bias0.y);
        v.z = gelu_exact(acc[i][2]+bias0.z); v.w = gelu_exact(acc[i][3]+bias0.w);
        *(float4*)(Cf + (size_t)m*N + o0) = v;
      }
      if (ok1){
        float4 v;
        v.x = gelu_exact(acc[i][4]+bias1.x); v.y = gelu_exact(acc[i][5]+bias1.y);
        v.z = gelu_exact(acc[i][6]+bias1.z); v.w = gelu_exact(acc[i][7]+bias1.w);
        *(float4*)(Cf + (size_t)m*N + o1) = v;
      }
    } else {
      if (ok0){
        float4 old = *(const float4*)(Cf + (size_t)m*N + o0);
        float4 v; v.x=old.x+acc[i][0]+bias0.x; v.y=old.y+acc[i][1]+bias0.y; v.z=old.z+acc[i][2]+bias0.z; v.w=old.w+acc[i][3]+bias0.w;
        *(float4*)(Cf + (size_t)m*N + o0) = v;
      }
      if (ok1){
        float4 old = *(const float4*)(Cf + (size_t)m*N + o1);
        float4 v; v.x=old.x+acc[i][4]+bias1.x; v.y=old.y+acc[i][5]+bias1.y; v.z=old.z+acc[i][6]+bias1.z; v.w=old.w+acc[i][7]+bias1.w;
        *(float4*)(Cf + (size_t)m*N + o1) = v;
      }
    }
  }
}

// ---------------- depthwise conv (k=9, edge pad) + LayerNorm over channels ----------------
__global__ __launch_bounds__(192) void dwconv_ln_kernel(
  const float* __restrict__ h, const float* __restrict__ dww, const float* __restrict__ dwb,
  const float* __restrict__ lnw, const float* __restrict__ lnb, float* __restrict__ yln)
{
  __shared__ float rs_[192], rq_[192], st[2];
  const int c  = threadIdx.x;
  const int bt = blockIdx.x;
  const int t  = bt & 511;
  const float* hb = h + (size_t)(bt & ~511) * H_;
  float acc = dwb[c];
  #pragma unroll
  for (int k=0;k<9;k++){
    int tt = t + k - 4; tt = tt < 0 ? 0 : (tt > 511 ? 511 : tt);
    acc += dww[c*9+k] * hb[(size_t)tt*H_ + c];
  }
  rs_[c] = acc; rq_[c] = acc*acc;
  __syncthreads();
  if (c < 64){
    float s = rs_[c]+rs_[c+64]+rs_[c+128];
    float q = rq_[c]+rq_[c+64]+rq_[c+128];
    #pragma unroll
    for (int off=32; off>0; off>>=1){ s += __shfl_down(s,off); q += __shfl_down(q,off); }
    if (c==0){ st[0]=s; st[1]=q; }
  }
  __syncthreads();
  float mean = st[0]*(1.f/H_);
  float var  = st[1]*(1.f/H_) - mean*mean;
  float r = rsqrtf(var + 1e-5f);
  yln[(size_t)bt*H_ + c] = (acc-mean)*r*lnw[c] + lnb[c];
}

// ---------------- output LayerNorm (+ save last-timestep row to hlast) ----------------
__global__ __launch_bounds__(192) void out_ln_kernel(
  const float* __restrict__ h, const float* __restrict__ lnw, const float* __restrict__ lnb,
  float* __restrict__ o, float* __restrict__ hlast, int b0)
{
  __shared__ float rs_[192], rq_[192], st[2];
  const int c  = threadIdx.x;
  const int bt = blockIdx.x;
  float v = h[(size_t)bt*H_ + c];
  rs_[c]=v; rq_[c]=v*v;
  __syncthreads();
  if (c < 64){
    float s = rs_[c]+rs_[c+64]+rs_[c+128];
    float q = rq_[c]+rq_[c+64]+rq_[c+128];
    #pragma unroll
    for (int off=32; off>0; off>>=1){ s += __shfl_down(s,off); q += __shfl_down(q,off); }
    if (c==0){ st[0]=s; st[1]=q; }
  }
  __syncthreads();
  float mean = st[0]*(1.f/H_);
  float var  = st[1]*(1.f/H_) - mean*mean;
  float r = rsqrtf(var + 1e-5f);
  float res = (v-mean)*r*lnw[c] + lnb[c];
  o[(size_t)bt*H_ + c] = res;
  if ((bt & 511) == 511) hlast[(size_t)(b0 + (bt>>9))*H_ + c] = res;
}

// ---------------- GRN stats: scale[b,c] = 1 + g[c]*gx/(mean_c(gx)+1e-6) ----------------
__global__ __launch_bounds__(384) void grn_stats_kernel(
  const float* __restrict__ y1, const float* __restrict__ grn_g, float* __restrict__ scale)
{
  __shared__ float r[384];
  const int c = threadIdx.x;
  const int b = blockIdx.x;
  const float* p = y1 + (size_t)b*Q_*HID_ + c;
  float s = 0.f;
  #pragma unroll 4
  for (int t=0;t<Q_;t++){ float v = p[(size_t)t*HID_]; s += v*v; }
  float gx = sqrtf(s);
  r[c] = gx;
  __syncthreads();
  if (c < 64){
    float v = r[c]+r[c+64]+r[c+128]+r[c+192]+r[c+256]+r[c+320];
    #pragma unroll
    for (int off=32; off>0; off>>=1) v += __shfl_down(v,off);
    if (c==0) r[0]=v;
  }
  __syncthreads();
  float mean = r[0]*(1.f/HID_);
  scale[(size_t)b*HID_ + c] = 1.f + grn_g[c]*gx/(mean + 1e-6f);
}

// ---------------- pack fc_rp / fc_gain into padded (64,192) W ----------------
__global__ void pack_w_kernel(const float* __restrict__ frw, const float* __restrict__ frb,
                              const float* __restrict__ fgw, const float* __restrict__ fgb,
                              float* __restrict__ w_pad, float* __restrict__ b_pad)
{
  int idx = blockIdx.x*256 + threadIdx.x;
  if (idx >= 64*192) return;
  int o = idx / 192, k = idx % 192;
  float v = 0.f;
  if (o < 2) v = frw[o*192+k]; else if (o < 34) v = fgw[(o-2)*192+k];
  w_pad[idx] = v;
  if (k == 0){
    float bv = 0.f;
    if (o < 2) bv = frb[o]; else if (o < 34) bv = fgb[o-2];
    b_pad[o] = bv;
  }
}

// ---------------- sequential Kalman scan (reads raw logits, stride 64) ----------------
__global__ __launch_bounds__(64) void kalman_scan_kernel(
  const float* __restrict__ x_c, const float* __restrict__ raw, float* __restrict__ xpost,
  int b0, int Bc)
{
  const int lane = threadIdx.x;
  const int bl = blockIdx.x*4 + (lane>>4);
  if (bl >= Bc) return;
  const int m = lane & 15;
  const float* xb = x_c + (size_t)bl*Q_*D_;
  const float* rb = raw + (size_t)bl*Q_*64;
  float re = xb[m], im = xb[16+m];
  for (int t=0;t<Q_;t++){
    const float* r = rb + (size_t)t*64;
    float rho = 1.25f*sigm(r[0]);
    float phi = PI_F*tanhf(r[1]);
    float rc = rho*cosf(phi), rs = rho*sinf(phi);
    float g0 = sigm(r[2+m]), g1 = sigm(r[18+m]);
    float y0 = xb[(size_t)t*D_ + m], y1v = xb[(size_t)t*D_ + 16 + m];
    float pr  = rc*re - rs*im;
    float pim = rs*re + rc*im;
    re = pr  + g0*(y0  - pr);
    im = pim + g1*(y1v - pim);
  }
  xpost[(b0+bl)*D_ + m] = re;
  xpost[(b0+bl)*D_ + 16 + m] = im;
}

// ---------------- rollout weight prep: wT1[k][o] + packed [k][o][8] gate block ----------------
__global__ void prep_rollout_kernel(const float* __restrict__ riw, const float* __restrict__ wih,
                                    const float* __restrict__ whh,
                                    float* __restrict__ wT1, float* __restrict__ wPack)
{
  int idx = blockIdx.x*256 + threadIdx.x;
  if (idx < 224*192){
    int o = idx % 192, k = idx / 192;
    wT1[idx] = riw[o*224 + k];
    return;
  }
  idx -= 224*192;
  if (idx < 192*192){
    int o = idx % 192, k = idx / 192;
    float* w = wPack + ((size_t)k*192 + o)*8;
    w[0] = wih[(0*192+o)*192 + k];
    w[1] = wih[(1*192+o)*192 + k];
    w[2] = wih[(2*192+o)*192 + k];
    w[3] = whh[(0*192+o)*192 + k];
    w[4] = whh[(1*192+o)*192 + k];
    w[5] = whh[(2*192+o)*192 + k];
    w[6] = 0.f; w[7] = 0.f;
  }
}

// ---------------- GRU rollout: BPB batches/block, packed weights, 64 steps ----------------
__global__ __launch_bounds__(192) void rollout_kernel(
  const float* __restrict__ hlast, const float* __restrict__ xpost,
  const float* __restrict__ wT1,  const float* __restrict__ rib_,
  const float* __restrict__ wPack,
  const float* __restrict__ bih,  const float* __restrict__ bhh,
  const float* __restrict__ lnw,  const float* __restrict__ lnb,
  const float* __restrict__ frw,  const float* __restrict__ frb,
  float* __restrict__ out)
{
  const int tid = threadIdx.x;
  const int bb = blockIdx.x*BPB;
  __shared__ float h[BPB][192], x[BPB][192], c[BPB][32];
  __shared__ float red1[BPB][192], red2[BPB][192];
  __shared__ float stL[BPB][2], stR[BPB][2];

  #pragma unroll
  for (int j=0;j<BPB;j++) h[j][tid] = hlast[(size_t)(bb+j)*H_ + tid];
  if (tid < 32){
    #pragma unroll
    for (int j=0;j<BPB;j++) c[j][tid] = xpost[(bb+j)*D_ + tid];
  }
  const float w_ln = lnw[tid], b_ln = lnb[tid];
  const float w_r0 = frw[tid], w_r1 = frw[192+tid];
  const float fb0 = frb[0], fb1 = frb[1];
  const float bi0 = bih[tid], bi1 = bih[192+tid], bi2 = bih[384+tid];
  const float bh0 = bhh[tid], bh1 = bhh[192+tid], bh2 = bhh[384+tid];
  const float rib = rib_[tid];
  __syncthreads();

  for (int s=0; s<WOUT_; s++){
    // phase A: x[j] = tanh(W1 @ [h_j; c_j] + b1) — weight load amortized over BPB
    float a[BPB];
    #pragma unroll
    for (int j=0;j<BPB;j++) a[j] = rib;
    #pragma unroll 4
    for (int k=0;k<192;k++){
      float w = wT1[k*192+tid];
      #pragma unroll
      for (int j=0;j<BPB;j++) a[j] += w*h[j][k];
    }
    #pragma unroll
    for (int k=0;k<32;k++){
      float w = wT1[(192+k)*192+tid];
      #pragma unroll
      for (int j=0;j<BPB;j++) a[j] += w*c[j][k];
    }
    #pragma unroll
    for (int j=0;j<BPB;j++) x[j][tid] = tanhf(a[j]);
    __syncthreads();

    // phase B: 6 gates × BPB batches per 32B of weights
    float p0[BPB], p1[BPB], p2[BPB], q0[BPB], q1[BPB], q2[BPB];
    #pragma unroll
    for (int j=0;j<BPB;j++){ p0[j]=bi0; p1[j]=bi1; p2[j]=bi2; q0[j]=bh0; q1[j]=bh1; q2[j]=bh2; }
    #pragma unroll 2
    for (int k=0;k<192;k++){
      const float4* wp = (const float4*)(wPack + ((size_t)k*192 + tid)*8);
      float4 wA = wp[0];
      float4 wB = wp[1];
      #pragma unroll
      for (int j=0;j<BPB;j++){
        float xv = x[j][k], hv = h[j][k];
        p0[j] += wA.x*xv; p1[j] += wA.y*xv; p2[j] += wA.z*xv;
        q0[j] += wA.w*hv; q1[j] += wB.x*hv; q2[j] += wB.y*hv;
      }
    }
    float pre[BPB];
    #pragma unroll
    for (int j=0;j<BPB;j++){
      float rg = sigm(p0[j]+q0[j]), z = sigm(p1[j]+q1[j]);
      float n  = tanhf(p2[j] + rg*q2[j]);
      pre[j] = (1.f - z)*n + z*h[j][tid];
      red1[j][tid] = pre[j]; red2[j][tid] = pre[j]*pre[j];
    }
    __syncthreads();
    if (tid < 64){
      #pragma unroll
      for (int j=0;j<BPB;j++){
        float s0 = red1[j][tid]+red1[j][tid+64]+red1[j][tid+128];
        float q0r= red2[j][tid]+red2[j][tid+64]+red2[j][tid+128];
        #pragma unroll
        for (int off=32; off>0; off>>=1){ s0 += __shfl_down(s0,off); q0r += __shfl_down(q0r,off); }
        if (tid==0){ stL[j][0]=s0; stL[j][1]=q0r; }
      }
    }
    __syncthreads();
    const float inv = 1.f/192.f;
    float hn[BPB];
    #pragma unroll
    for (int j=0;j<BPB;j++){
      float mu = stL[j][0]*inv, var = stL[j][1]*inv - mu*mu;
      hn[j] = (pre[j]-mu)*rsqrtf(var+1e-5f)*w_ln + b_ln;
      h[j][tid] = hn[j];
      red1[j][tid] = hn[j]*w_r0; red2[j][tid] = hn[j]*w_r1;
    }
    __syncthreads();
    if (tid < 64){
      #pragma unroll
      for (int j=0;j<BPB;j++){
        float s0 = red1[j][tid]+red1[j][tid+64]+red1[j][tid+128];
        float q0r= red2[j][tid]+red2[j][tid+64]+red2[j][tid+128];
        #pragma unroll
        for (int off=32; off>0; off>>=1){ s0 += __shfl_down(s0,off); q0r += __shfl_down(q0r,off); }
        if (tid==0){ stR[j][0]=s0; stR[j][1]=q0r; }
      }
    }
    __syncthreads();
    if (tid < 16){
      #pragma unroll
      for (int j=0;j<BPB;j++){
        float rho = 1.25f*sigm(stR[j][0]+fb0);
        float phi = PI_F*tanhf(stR[j][1]+fb1);
        float rc = rho*cosf(phi), rs = rho*sinf(phi);
        float re = c[j][tid], im = c[j][tid+16];
        float nre = rc*re - rs*im;
        float nim = rs*re + rc*im;
        c[j][tid] = nre; c[j][tid+16] = nim;
        float* ob = out + ((size_t)(bb+j)*WOUT_ + s)*D_;
        ob[tid] = nre; ob[tid+16] = nim;
      }
    }
    __syncthreads();
  }
}

// ---------------- host launch ----------------
extern "C" void kernel_launch(void* const* d_in, const int* in_sizes, int n_in,
                              void* d_out, int out_size, void* d_ws, size_t ws_size,
                              hipStream_t stream)
{
  const float* x_in     = (const float*)d_in[0];
  const float* inp_w    = (const float*)d_in[1];
  const float* inp_b    = (const float*)d_in[2];
  const float* b_dw_w   = (const float*)d_in[3];
  const float* b_dw_b   = (const float*)d_in[4];
  const float* b_ln_w   = (const float*)d_in[5];
  const float* b_ln_b   = (const float*)d_in[6];
  const float* b_pw1_w  = (const float*)d_in[7];
  const float* b_pw1_b  = (const float*)d_in[8];
  const float* b_grn_g  = (const float*)d_in[9];
  const float* b_grn_b  = (const float*)d_in[10];
  const float* b_pw2_w  = (const float*)d_in[11];
  const float* b_pw2_b  = (const float*)d_in[12];
  const float* out_ln_w = (const float*)d_in[13];
  const float* out_ln_b = (const float*)d_in[14];
  const float* fc_rp_w  = (const float*)d_in[15];
  const float* fc_rp_b  = (const float*)d_in[16];
  const float* fc_gain_w= (const float*)d_in[17];
  const float* fc_gain_b= (const float*)d_in[18];
  const float* roll_in_w= (const float*)d_in[19];
  const float* roll_in_b= (const float*)d_in[20];
  const float* gru_wih  = (const float*)d_in[21];
  const float* gru_whh  = (const float*)d_in[22];
  const float* gru_bih  = (const float*)d_in[23];
  const float* gru_bhh  = (const float*)d_in[24];
  const float* roll_ln_w= (const float*)d_in[25];
  const float* roll_ln_b= (const float*)d_in[26];
  const float* fc_rp_r_w= (const float*)d_in[27];
  const float* fc_rp_r_b= (const float*)d_in[28];
  float* out = (float*)d_out;

  // ---- adaptive chunking ----
  // per-row floats: h(192) + yln(192) + mid(384; feats/y1/rpraw alias) = 768
  // fixed tail: scaleB 98304 + w_pad 12288 + b_pad 64 + xpost 8192 + hlast 49152
  //           + wT1 43008 + wPack 294912 = 505920 ; +4096 margin
  const size_t SMAL_FLOATS = 505920 + 4096;
  size_t ws_floats = ws_size / 4;
  int nchunk = 256;
  const int cand[9] = {1,2,4,8,16,32,64,128,256};
  for (int ci=0; ci<9; ci++){
    size_t Mc_try = (size_t)M_ / cand[ci];
    if (Mc_try*768 + SMAL_FLOATS <= ws_floats){ nchunk = cand[ci]; break; }
  }
  const int    Bc = B_ / nchunk;
  const size_t Mc = (size_t)Bc * Q_;

  float* ws    = (float*)d_ws;
  float* h_c   = ws;                     // Mc*192
  float* yln_c = h_c   + Mc*192;         // Mc*192 (also h_seq per chunk)
  float* mid_c = yln_c + Mc*192;         // Mc*384: feats / y1 fp32 / rpraw (sequential lifetimes)
  float* smal  = mid_c + Mc*384;

  float* feats_c = mid_c;
  float* y1_c    = mid_c;
  float* rpraw   = mid_c;                // alias: y1 dead when kalman gemm runs

  float* scaleB = smal;                  // Bc*384 (reserve 98304)
  float* w_pad  = smal + 98304;          // 64*192
  float* b_pad  = w_pad + 12288;         // 64
  float* xpost  = b_pad + 64;            // B_*32
  float* hlast  = xpost + 8192;          // B_*192
  float* wT1    = hlast + 49152;         // 224*192
  float* wPack  = wT1 + 43008;           // 192*192*8

  // one-time weight prep
  pack_w_kernel<<<(64*192+255)/256, 256, 0, stream>>>(fc_rp_w, fc_rp_b, fc_gain_w, fc_gain_b, w_pad, b_pad);
  prep_rollout_kernel<<<(224*192+192*192+255)/256, 256, 0, stream>>>(roll_in_w, gru_wih, gru_whh, wT1, wPack);

  const int gemm_mx = (int)(Mc/64);
  for (int ch=0; ch<nchunk; ch++){
    const float* x_c = x_in + (size_t)ch*Mc*D_;
    // 1. features + input projection
    feats_kernel<<<(int)((Mc*32+255)/256), 256, 0, stream>>>(x_c, feats_c, (int)Mc);
    gemm64<0><<<dim3(gemm_mx, 2), 256, 0, stream>>>(feats_c, inp_w, inp_b,
                                                    h_c, nullptr, nullptr, H_, INCH_);
    // 2. ConvNeXt blocks
    for (int blk = 0; blk < 2; blk++){
      const float* dww = b_dw_w + blk*H_*9;     const float* dwb = b_dw_b + blk*H_;
      const float* lnw = b_ln_w + blk*H_;       const float* lnb = b_ln_b + blk*H_;
      const float* p1w = b_pw1_w + blk*HID_*H_; const float* p1b = b_pw1_b + blk*HID_;
      const float* gg  = b_grn_g + blk*HID_;    const float* gb  = b_grn_b + blk*HID_;
      const float* p2w = b_pw2_w + blk*H_*HID_; const float* p2b = b_pw2_b + blk*H_;
      dwconv_ln_kernel<<<(int)Mc, 192, 0, stream>>>(h_c, dww, dwb, lnw, lnb, yln_c);
      gemm64<1><<<dim3(gemm_mx, 3), 256, 0, stream>>>(yln_c, p1w, p1b,
                                                      y1_c, nullptr, nullptr, HID_, H_);
      grn_stats_kernel<<<Bc, 384, 0, stream>>>(y1_c, gg, scaleB);
      gemm64<2><<<dim3(gemm_mx, 2), 256, 0, stream>>>(y1_c, p2w, p2b,
                                                      h_c, scaleB, gb, H_, HID_);
    }
    // 3. output LN -> h_seq (reuse yln_c), save last-t rows
    out_ln_kernel<<<(int)Mc, 192, 0, stream>>>(h_c, out_ln_w, out_ln_b, yln_c, hlast, ch*Bc);
    // 4. Kalman projection + sequential scan (rpraw aliases dead y1)
    gemm64<0><<<dim3(gemm_mx, 1), 256, 0, stream>>>(yln_c, w_pad, b_pad,
                                                    rpraw, nullptr, nullptr, 64, H_);
    kalman_scan_kernel<<<(Bc+3)/4, 64, 0, stream>>>(x_c, rpraw, xpost, ch*Bc, Bc);
  }
  // 5. GRU rollout (all batches, BPB per block)
  rollout_kernel<<<B_/BPB, 192, 0, stream>>>(hlast, xpost, wT1, roll_in_b, wPack,
                                             gru_bih, gru_bhh, roll_ln_w, roll_ln_b,
                                             fc_rp_r_w, fc_rp_r_b, out);
  (void)in_sizes; (void)n_in; (void)out_size; (void)ws_size;
}

// Round 5
// 3544.649 us; speedup vs baseline: 1.8701x; 1.2804x over previous
//
#include <hip/hip_runtime.h>
#include <cstdint>
#include <cstddef>

#define B_    256
#define Q_    512
#define D_    32
#define H_    192
#define HID_  384
#define INCH_ 96
#define M_    (B_*Q_)    // 131072
#define WOUT_ 64
#define BPB   4          // batches per rollout block
#define RT_   384        // rollout threads (split-K 2-way over 192 outputs)
#define PI_F  3.14159265358979323846f

__device__ __forceinline__ float sigm(float x){ return 1.f/(1.f+expf(-x)); }
__device__ __forceinline__ float gelu_exact(float x){ return 0.5f*x*(1.f+erff(x*0.7071067811865475f)); }

// ---------------- features: [x, dy, ddy]  (chunk of nrows rows) ----------------
__global__ void feats_kernel(const float* __restrict__ x, float* __restrict__ feats, int nrows){
  int idx = blockIdx.x*256 + threadIdx.x;
  if (idx >= nrows*32) return;
  int d  = idx & 31;
  int bt = idx >> 5;
  int t  = bt & 511;
  const float* xr = x + (size_t)bt*D_;
  float xc  = xr[d];
  float xm1 = (t>0) ? xr[d - D_]   : 0.f;
  float xm2 = (t>1) ? xr[d - 2*D_] : 0.f;
  float dy   = (t>0) ? xc - xm1   : 0.f;
  float dym1 = (t>1) ? xm1 - xm2  : 0.f;
  float ddy  = (t>0) ? dy - dym1  : 0.f;
  float* fr = feats + (size_t)bt*INCH_;
  fr[d] = xc; fr[D_+d] = dy; fr[2*D_+d] = ddy;
}

// ---------------- 64x128x8 fp32 tiled GEMM ----------------
// C[m,o] = sum_c A[m,c]*W[o,c] (+epilogue). A (Mc,K) row-major, W (N,K) row-major.
// MODE 0: out = acc + bias ; MODE 1: out = gelu(acc+bias) ; MODE 2: A affine, C += acc+bias
template<int MODE>
__global__ __launch_bounds__(256,4) void gemm64(
    const float* __restrict__ Af,
    const float* __restrict__ W,  const float* __restrict__ bias,
    float* __restrict__ Cf,
    const float* __restrict__ scale, const float* __restrict__ grnb,
    int N, int K)
{
  __shared__ float As[8][64];
  __shared__ float Bs[8][128];
  const int tid = threadIdx.x;
  const int bm = blockIdx.x * 64;
  const int bn = blockIdx.y * 128;
  const int tx = tid & 15, ty = tid >> 4;
  const int brow = tid >> 1, lk = (tid & 1) * 4;
  const int arow = (tid & 127) >> 1;

  float acc[4][8];
  #pragma unroll
  for (int i=0;i<4;i++)
    #pragma unroll
    for (int j=0;j<8;j++) acc[i][j]=0.f;

  const float* srow = (MODE==2) ? (scale + (size_t)(bm >> 9) * HID_) : nullptr;
  const bool brow_ok = (bn + brow) < N;
  const bool aload   = tid < 128;

  for (int k0 = 0; k0 < K; k0 += 8){
    float4 av = make_float4(0.f,0.f,0.f,0.f);
    if (aload){
      av = *(const float4*)(Af + (size_t)(bm+arow)*K + k0 + lk);
      if (MODE==2){
        int c = k0 + lk;
        float4 sc = *(const float4*)(srow + c);
        float4 gb = *(const float4*)(grnb + c);
        av.x = av.x*sc.x + gb.x; av.y = av.y*sc.y + gb.y;
        av.z = av.z*sc.z + gb.z; av.w = av.w*sc.w + gb.w;
      }
    }
    float4 bv = make_float4(0.f,0.f,0.f,0.f);
    if (brow_ok) bv = *(const float4*)(W + (size_t)(bn+brow)*K + k0 + lk);

    if (aload){
      As[lk+0][arow]=av.x; As[lk+1][arow]=av.y; As[lk+2][arow]=av.z; As[lk+3][arow]=av.w;
    }
    Bs[lk+0][brow]=bv.x; Bs[lk+1][brow]=bv.y; Bs[lk+2][brow]=bv.z; Bs[lk+3][brow]=bv.w;
    __syncthreads();
    #pragma unroll
    for (int kk=0;kk<8;kk++){
      float a[4], b[8];
      *(float4*)&a[0] = *(const float4*)&As[kk][ty*4];
      *(float4*)&b[0] = *(const float4*)&Bs[kk][tx*4];
      *(float4*)&b[4] = *(const float4*)&Bs[kk][64+tx*4];
      #pragma unroll
      for (int i=0;i<4;i++)
        #pragma unroll
        for (int j=0;j<8;j++) acc[i][j] += a[i]*b[j];
    }
    __syncthreads();
  }

  const bool ok0 = (bn + 64)  <= N;
  const bool ok1 = (bn + 128) <= N;
  const int o0 = bn + tx*4, o1 = bn + 64 + tx*4;
  float4 bias0 = make_float4(0,0,0,0), bias1 = make_float4(0,0,0,0);
  if (ok0) bias0 = *(const float4*)(bias + o0);
  if (ok1) bias1 = *(const float4*)(bias + o1);

  #pragma unroll
  for (int i=0;i<4;i++){
    int m = bm + ty*4 + i;
    if (MODE==0){
      if (ok0){
        float4 v; v.x=acc[i][0]+bias0.x; v.y=acc[i][1]+bias0.y; v.z=acc[i][2]+bias0.z; v.w=acc[i][3]+bias0.w;
        *(float4*)(Cf + (size_t)m*N + o0) = v;
      }
      if (ok1){
        float4 v; v.x=acc[i][4]+bias1.x; v.y=acc[i][5]+bias1.y; v.z=acc[i][6]+bias1.z; v.w=acc[i][7]+bias1.w;
        *(float4*)(Cf + (size_t)m*N + o1) = v;
      }
    } else if (MODE==1){
      if (ok0){
        float4 v;
        v.x = gelu_exact(acc[i][0]+bias0.x); v.y = gelu_exact(acc[i][1]+bias0.y);
        v.z = gelu_exact(acc[i][2]+bias0.z); v.w = gelu_exact(acc[i][3]+bias0.w);
        *(float4*)(Cf + (size_t)m*N + o0) = v;
      }
      if (ok1){
        float4 v;
        v.x = gelu_exact(acc[i][4]+bias1.x); v.y = gelu_exact(acc[i][5]+bias1.y);
        v.z = gelu_exact(acc[i][6]+bias1.z); v.w = gelu_exact(acc[i][7]+bias1.w);
        *(float4*)(Cf + (size_t)m*N + o1) = v;
      }
    } else {
      if (ok0){
        float4 old = *(const float4*)(Cf + (size_t)m*N + o0);
        float4 v; v.x=old.x+acc[i][0]+bias0.x; v.y=old.y+acc[i][1]+bias0.y; v.z=old.z+acc[i][2]+bias0.z; v.w=old.w+acc[i][3]+bias0.w;
        *(float4*)(Cf + (size_t)m*N + o0) = v;
      }
      if (ok1){
        float4 old = *(const float4*)(Cf + (size_t)m*N + o1);
        float4 v; v.x=old.x+acc[i][4]+bias1.x; v.y=old.y+acc[i][5]+bias1.y; v.z=old.z+acc[i][6]+bias1.z; v.w=old.w+acc[i][7]+bias1.w;
        *(float4*)(Cf + (size_t)m*N + o1) = v;
      }
    }
  }
}

// ---------------- depthwise conv (k=9, edge pad) + LayerNorm over channels ----------------
__global__ __launch_bounds__(192) void dwconv_ln_kernel(
  const float* __restrict__ h, const float* __restrict__ dww, const float* __restrict__ dwb,
  const float* __restrict__ lnw, const float* __restrict__ lnb, float* __restrict__ yln)
{
  __shared__ float rs_[192], rq_[192], st[2];
  const int c  = threadIdx.x;
  const int bt = blockIdx.x;
  const int t  = bt & 511;
  const float* hb = h + (size_t)(bt & ~511) * H_;
  float acc = dwb[c];
  #pragma unroll
  for (int k=0;k<9;k++){
    int tt = t + k - 4; tt = tt < 0 ? 0 : (tt > 511 ? 511 : tt);
    acc += dww[c*9+k] * hb[(size_t)tt*H_ + c];
  }
  rs_[c] = acc; rq_[c] = acc*acc;
  __syncthreads();
  if (c < 64){
    float s = rs_[c]+rs_[c+64]+rs_[c+128];
    float q = rq_[c]+rq_[c+64]+rq_[c+128];
    #pragma unroll
    for (int off=32; off>0; off>>=1){ s += __shfl_down(s,off); q += __shfl_down(q,off); }
    if (c==0){ st[0]=s; st[1]=q; }
  }
  __syncthreads();
  float mean = st[0]*(1.f/H_);
  float var  = st[1]*(1.f/H_) - mean*mean;
  float r = rsqrtf(var + 1e-5f);
  yln[(size_t)bt*H_ + c] = (acc-mean)*r*lnw[c] + lnb[c];
}

// ---------------- output LayerNorm (+ save last-timestep row to hlast) ----------------
__global__ __launch_bounds__(192) void out_ln_kernel(
  const float* __restrict__ h, const float* __restrict__ lnw, const float* __restrict__ lnb,
  float* __restrict__ o, float* __restrict__ hlast, int b0)
{
  __shared__ float rs_[192], rq_[192], st[2];
  const int c  = threadIdx.x;
  const int bt = blockIdx.x;
  float v = h[(size_t)bt*H_ + c];
  rs_[c]=v; rq_[c]=v*v;
  __syncthreads();
  if (c < 64){
    float s = rs_[c]+rs_[c+64]+rs_[c+128];
    float q = rq_[c]+rq_[c+64]+rq_[c+128];
    #pragma unroll
    for (int off=32; off>0; off>>=1){ s += __shfl_down(s,off); q += __shfl_down(q,off); }
    if (c==0){ st[0]=s; st[1]=q; }
  }
  __syncthreads();
  float mean = st[0]*(1.f/H_);
  float var  = st[1]*(1.f/H_) - mean*mean;
  float r = rsqrtf(var + 1e-5f);
  float res = (v-mean)*r*lnw[c] + lnb[c];
  o[(size_t)bt*H_ + c] = res;
  if ((bt & 511) == 511) hlast[(size_t)(b0 + (bt>>9))*H_ + c] = res;
}

// ---------------- GRN stats: scale[b,c] = 1 + g[c]*gx/(mean_c(gx)+1e-6) ----------------
__global__ __launch_bounds__(384) void grn_stats_kernel(
  const float* __restrict__ y1, const float* __restrict__ grn_g, float* __restrict__ scale)
{
  __shared__ float r[384];
  const int c = threadIdx.x;
  const int b = blockIdx.x;
  const float* p = y1 + (size_t)b*Q_*HID_ + c;
  float s = 0.f;
  #pragma unroll 4
  for (int t=0;t<Q_;t++){ float v = p[(size_t)t*HID_]; s += v*v; }
  float gx = sqrtf(s);
  r[c] = gx;
  __syncthreads();
  if (c < 64){
    float v = r[c]+r[c+64]+r[c+128]+r[c+192]+r[c+256]+r[c+320];
    #pragma unroll
    for (int off=32; off>0; off>>=1) v += __shfl_down(v,off);
    if (c==0) r[0]=v;
  }
  __syncthreads();
  float mean = r[0]*(1.f/HID_);
  scale[(size_t)b*HID_ + c] = 1.f + grn_g[c]*gx/(mean + 1e-6f);
}

// ---------------- pack fc_rp / fc_gain into padded (64,192) W ----------------
__global__ void pack_w_kernel(const float* __restrict__ frw, const float* __restrict__ frb,
                              const float* __restrict__ fgw, const float* __restrict__ fgb,
                              float* __restrict__ w_pad, float* __restrict__ b_pad)
{
  int idx = blockIdx.x*256 + threadIdx.x;
  if (idx >= 64*192) return;
  int o = idx / 192, k = idx % 192;
  float v = 0.f;
  if (o < 2) v = frw[o*192+k]; else if (o < 34) v = fgw[(o-2)*192+k];
  w_pad[idx] = v;
  if (k == 0){
    float bv = 0.f;
    if (o < 2) bv = frb[o]; else if (o < 34) bv = fgb[o-2];
    b_pad[o] = bv;
  }
}

// ---------------- wide Kalman prep: raw (Mc,64) -> rp (Mc,34) ----------------
// rp = [rho*cos(phi), rho*sin(phi), sigm(gain 0..31)] — all transcendentals done here, M-parallel
__global__ void kalman_prep_kernel(const float* __restrict__ raw, float* __restrict__ rp, int nrows){
  int idx = blockIdx.x*256 + threadIdx.x;
  if (idx >= nrows*32) return;
  int d  = idx & 31;
  int bt = idx >> 5;
  const float* r = raw + (size_t)bt*64;
  float* o = rp + (size_t)bt*34;
  o[2+d] = sigm(r[2+d]);
  if (d==0){
    float rho = 1.25f*sigm(r[0]);
    float phi = PI_F * tanhf(r[1]);
    o[0] = rho*cosf(phi);
    o[1] = rho*sinf(phi);
  }
}

// ---------------- sequential Kalman scan — FMA-only inner loop ----------------
__global__ __launch_bounds__(64) void kalman_scan_kernel(
  const float* __restrict__ x_c, const float* __restrict__ rp, float* __restrict__ xpost,
  int b0, int Bc)
{
  const int lane = threadIdx.x;
  const int bl = blockIdx.x*4 + (lane>>4);
  if (bl >= Bc) return;
  const int m = lane & 15;
  const float* xb  = x_c + (size_t)bl*Q_*D_;
  const float* rpb = rp  + (size_t)bl*Q_*34;
  float re = xb[m], im = xb[16+m];
  for (int t=0;t<Q_;t++){
    const float* r = rpb + (size_t)t*34;
    float rc = r[0], rs = r[1];
    float g0 = r[2+m], g1 = r[18+m];
    float y0 = xb[(size_t)t*D_ + m], y1v = xb[(size_t)t*D_ + 16 + m];
    float pr  = rc*re - rs*im;
    float pim = rs*re + rc*im;
    re = pr  + g0*(y0  - pr);
    im = pim + g1*(y1v - pim);
  }
  xpost[(b0+bl)*D_ + m] = re;
  xpost[(b0+bl)*D_ + 16 + m] = im;
}

// ---------------- rollout weight prep: wT1[k][o] + packed [k][o][8] gate block ----------------
__global__ void prep_rollout_kernel(const float* __restrict__ riw, const float* __restrict__ wih,
                                    const float* __restrict__ whh,
                                    float* __restrict__ wT1, float* __restrict__ wPack)
{
  int idx = blockIdx.x*256 + threadIdx.x;
  if (idx < 224*192){
    int o = idx % 192, k = idx / 192;
    wT1[idx] = riw[o*224 + k];
    return;
  }
  idx -= 224*192;
  if (idx < 192*192){
    int o = idx % 192, k = idx / 192;
    float* w = wPack + ((size_t)k*192 + o)*8;
    w[0] = wih[(0*192+o)*192 + k];
    w[1] = wih[(1*192+o)*192 + k];
    w[2] = wih[(2*192+o)*192 + k];
    w[3] = whh[(0*192+o)*192 + k];
    w[4] = whh[(1*192+o)*192 + k];
    w[5] = whh[(2*192+o)*192 + k];
    w[6] = 0.f; w[7] = 0.f;
  }
}

// ---------------- GRU rollout: BPB batches/block, 384 threads split-K 2-way ----------------
__global__ __launch_bounds__(RT_) void rollout_kernel(
  const float* __restrict__ hlast, const float* __restrict__ xpost,
  const float* __restrict__ wT1,  const float* __restrict__ rib_,
  const float* __restrict__ wPack,
  const float* __restrict__ bih,  const float* __restrict__ bhh,
  const float* __restrict__ lnw,  const float* __restrict__ lnb,
  const float* __restrict__ frw,  const float* __restrict__ frb,
  float* __restrict__ out)
{
  const int tid  = threadIdx.x;
  const int half = (tid >= 192) ? 1 : 0;   // wave-aligned split (192 = 3 waves)
  const int o    = tid - half*192;
  const int bb   = blockIdx.x*BPB;
  __shared__ float h[BPB][192], x[BPB][192], c[BPB][32];
  __shared__ float pA[192][BPB+1];         // +1 pad: stride 5 vs 32 banks -> conflict-free
  __shared__ float pB[192][25];            // 24 partials + pad: stride 25 coprime w/ 32
  __shared__ float red1[BPB][192], red2[BPB][192];
  __shared__ float stL[BPB][2], stR[BPB][2];

  if (half==0){
    #pragma unroll
    for (int j=0;j<BPB;j++) h[j][o] = hlast[(size_t)(bb+j)*H_ + o];
  }
  if (tid < 32){
    #pragma unroll
    for (int j=0;j<BPB;j++) c[j][tid] = xpost[(bb+j)*D_ + tid];
  }
  const float w_ln = lnw[o], b_ln = lnb[o];
  const float w_r0 = frw[o], w_r1 = frw[192+o];
  const float fb0 = frb[0], fb1 = frb[1];
  const float bi0 = bih[o], bi1 = bih[192+o], bi2 = bih[384+o];
  const float bh0 = bhh[o], bh1 = bhh[192+o], bh2 = bhh[384+o];
  const float rib = rib_[o];
  __syncthreads();

  for (int s=0; s<WOUT_; s++){
    // ---- phase A: x = tanh(W1 @ [h; c] + b1), K split 0..111 / 112..223 ----
    float a[BPB];
    if (half==0){
      #pragma unroll
      for (int j=0;j<BPB;j++) a[j] = rib;
      #pragma unroll 4
      for (int k=0;k<112;k++){
        float w = wT1[k*192+o];
        #pragma unroll
        for (int j=0;j<BPB;j++) a[j] += w*h[j][k];
      }
    } else {
      #pragma unroll
      for (int j=0;j<BPB;j++) a[j] = 0.f;
      #pragma unroll 4
      for (int k=112;k<192;k++){
        float w = wT1[k*192+o];
        #pragma unroll
        for (int j=0;j<BPB;j++) a[j] += w*h[j][k];
      }
      #pragma unroll
      for (int k=0;k<32;k++){
        float w = wT1[(192+k)*192+o];
        #pragma unroll
        for (int j=0;j<BPB;j++) a[j] += w*c[j][k];
      }
      #pragma unroll
      for (int j=0;j<BPB;j++) pA[o][j] = a[j];
    }
    __syncthreads();
    if (half==0){
      #pragma unroll
      for (int j=0;j<BPB;j++) x[j][o] = tanhf(a[j] + pA[o][j]);
    }
    __syncthreads();

    // ---- phase B: 6 gates, K split 0..95 / 96..191 ----
    float p0[BPB], p1[BPB], p2[BPB], q0[BPB], q1[BPB], q2[BPB];
    #pragma unroll
    for (int j=0;j<BPB;j++){
      p0[j] = half ? 0.f : bi0; p1[j] = half ? 0.f : bi1; p2[j] = half ? 0.f : bi2;
      q0[j] = half ? 0.f : bh0; q1[j] = half ? 0.f : bh1; q2[j] = half ? 0.f : bh2;
    }
    const int kb = half*96;
    #pragma unroll 2
    for (int k=kb;k<kb+96;k++){
      const float4* wp = (const float4*)(wPack + ((size_t)k*192 + o)*8);
      float4 wA = wp[0];
      float4 wB = wp[1];
      #pragma unroll
      for (int j=0;j<BPB;j++){
        float xv = x[j][k], hv = h[j][k];
        p0[j] += wA.x*xv; p1[j] += wA.y*xv; p2[j] += wA.z*xv;
        q0[j] += wA.w*hv; q1[j] += wB.x*hv; q2[j] += wB.y*hv;
      }
    }
    if (half==1){
      #pragma unroll
      for (int j=0;j<BPB;j++){
        pB[o][j*6+0]=p0[j]; pB[o][j*6+1]=p1[j]; pB[o][j*6+2]=p2[j];
        pB[o][j*6+3]=q0[j]; pB[o][j*6+4]=q1[j]; pB[o][j*6+5]=q2[j];
      }
    }
    __syncthreads();
    float pre[BPB];
    if (half==0){
      #pragma unroll
      for (int j=0;j<BPB;j++){
        float P0=p0[j]+pB[o][j*6+0], P1=p1[j]+pB[o][j*6+1], P2=p2[j]+pB[o][j*6+2];
        float Q0=q0[j]+pB[o][j*6+3], Q1=q1[j]+pB[o][j*6+4], Q2=q2[j]+pB[o][j*6+5];
        float rg = sigm(P0+Q0), z = sigm(P1+Q1);
        float n  = tanhf(P2 + rg*Q2);
        pre[j] = (1.f - z)*n + z*h[j][o];
        red1[j][o] = pre[j]; red2[j][o] = pre[j]*pre[j];
      }
    }
    __syncthreads();
    if (tid < 64){
      #pragma unroll
      for (int j=0;j<BPB;j++){
        float s0 = red1[j][tid]+red1[j][tid+64]+red1[j][tid+128];
        float q0r= red2[j][tid]+red2[j][tid+64]+red2[j][tid+128];
        #pragma unroll
        for (int off=32; off>0; off>>=1){ s0 += __shfl_down(s0,off); q0r += __shfl_down(q0r,off); }
        if (tid==0){ stL[j][0]=s0; stL[j][1]=q0r; }
      }
    }
    __syncthreads();
    if (half==0){
      const float inv = 1.f/192.f;
      #pragma unroll
      for (int j=0;j<BPB;j++){
        float mu = stL[j][0]*inv, var = stL[j][1]*inv - mu*mu;
        float hn = (pre[j]-mu)*rsqrtf(var+1e-5f)*w_ln + b_ln;
        h[j][o] = hn;
        red1[j][o] = hn*w_r0; red2[j][o] = hn*w_r1;
      }
    }
    __syncthreads();
    if (tid < 64){
      #pragma unroll
      for (int j=0;j<BPB;j++){
        float s0 = red1[j][tid]+red1[j][tid+64]+red1[j][tid+128];
        float q0r= red2[j][tid]+red2[j][tid+64]+red2[j][tid+128];
        #pragma unroll
        for (int off=32; off>0; off>>=1){ s0 += __shfl_down(s0,off); q0r += __shfl_down(q0r,off); }
        if (tid==0){ stR[j][0]=s0; stR[j][1]=q0r; }
      }
    }
    __syncthreads();
    if (tid < 16){
      #pragma unroll
      for (int j=0;j<BPB;j++){
        float rho = 1.25f*sigm(stR[j][0]+fb0);
        float phi = PI_F*tanhf(stR[j][1]+fb1);
        float rc = rho*cosf(phi), rs = rho*sinf(phi);
        float re = c[j][tid], im = c[j][tid+16];
        float nre = rc*re - rs*im;
        float nim = rs*re + rc*im;
        c[j][tid] = nre; c[j][tid+16] = nim;
        float* ob = out + ((size_t)(bb+j)*WOUT_ + s)*D_;
        ob[tid] = nre; ob[tid+16] = nim;
      }
    }
    __syncthreads();
  }
}

// ---------------- host launch ----------------
extern "C" void kernel_launch(void* const* d_in, const int* in_sizes, int n_in,
                              void* d_out, int out_size, void* d_ws, size_t ws_size,
                              hipStream_t stream)
{
  const float* x_in     = (const float*)d_in[0];
  const float* inp_w    = (const float*)d_in[1];
  const float* inp_b    = (const float*)d_in[2];
  const float* b_dw_w   = (const float*)d_in[3];
  const float* b_dw_b   = (const float*)d_in[4];
  const float* b_ln_w   = (const float*)d_in[5];
  const float* b_ln_b   = (const float*)d_in[6];
  const float* b_pw1_w  = (const float*)d_in[7];
  const float* b_pw1_b  = (const float*)d_in[8];
  const float* b_grn_g  = (const float*)d_in[9];
  const float* b_grn_b  = (const float*)d_in[10];
  const float* b_pw2_w  = (const float*)d_in[11];
  const float* b_pw2_b  = (const float*)d_in[12];
  const float* out_ln_w = (const float*)d_in[13];
  const float* out_ln_b = (const float*)d_in[14];
  const float* fc_rp_w  = (const float*)d_in[15];
  const float* fc_rp_b  = (const float*)d_in[16];
  const float* fc_gain_w= (const float*)d_in[17];
  const float* fc_gain_b= (const float*)d_in[18];
  const float* roll_in_w= (const float*)d_in[19];
  const float* roll_in_b= (const float*)d_in[20];
  const float* gru_wih  = (const float*)d_in[21];
  const float* gru_whh  = (const float*)d_in[22];
  const float* gru_bih  = (const float*)d_in[23];
  const float* gru_bhh  = (const float*)d_in[24];
  const float* roll_ln_w= (const float*)d_in[25];
  const float* roll_ln_b= (const float*)d_in[26];
  const float* fc_rp_r_w= (const float*)d_in[27];
  const float* fc_rp_r_b= (const float*)d_in[28];
  float* out = (float*)d_out;

  // ---- adaptive chunking ----
  // per-row floats: h(192) + yln(192) + mid(384; feats/y1, then rpraw(64)+rp(34)) = 768
  // fixed tail: scaleB 98304 + w_pad 12288 + b_pad 64 + xpost 8192 + hlast 49152
  //           + wT1 43008 + wPack 294912 = 505920 ; +4096 margin
  const size_t SMAL_FLOATS = 505920 + 4096;
  size_t ws_floats = ws_size / 4;
  int nchunk = 256;
  const int cand[9] = {1,2,4,8,16,32,64,128,256};
  for (int ci=0; ci<9; ci++){
    size_t Mc_try = (size_t)M_ / cand[ci];
    if (Mc_try*768 + SMAL_FLOATS <= ws_floats){ nchunk = cand[ci]; break; }
  }
  const int    Bc = B_ / nchunk;
  const size_t Mc = (size_t)Bc * Q_;

  float* ws    = (float*)d_ws;
  float* h_c   = ws;                     // Mc*192
  float* yln_c = h_c   + Mc*192;         // Mc*192 (also h_seq per chunk)
  float* mid_c = yln_c + Mc*192;         // Mc*384: feats / y1 fp32 / (rpraw + rp)
  float* smal  = mid_c + Mc*384;

  float* feats_c = mid_c;
  float* y1_c    = mid_c;
  float* rpraw   = mid_c;                // Mc*64 (y1 dead by then)
  float* rp_c    = mid_c + Mc*64;        // Mc*34

  float* scaleB = smal;                  // Bc*384 (reserve 98304)
  float* w_pad  = smal + 98304;          // 64*192
  float* b_pad  = w_pad + 12288;         // 64
  float* xpost  = b_pad + 64;            // B_*32
  float* hlast  = xpost + 8192;          // B_*192
  float* wT1    = hlast + 49152;         // 224*192
  float* wPack  = wT1 + 43008;           // 192*192*8

  // one-time weight prep
  pack_w_kernel<<<(64*192+255)/256, 256, 0, stream>>>(fc_rp_w, fc_rp_b, fc_gain_w, fc_gain_b, w_pad, b_pad);
  prep_rollout_kernel<<<(224*192+192*192+255)/256, 256, 0, stream>>>(roll_in_w, gru_wih, gru_whh, wT1, wPack);

  const int gemm_mx = (int)(Mc/64);
  for (int ch=0; ch<nchunk; ch++){
    const float* x_c = x_in + (size_t)ch*Mc*D_;
    // 1. features + input projection
    feats_kernel<<<(int)((Mc*32+255)/256), 256, 0, stream>>>(x_c, feats_c, (int)Mc);
    gemm64<0><<<dim3(gemm_mx, 2), 256, 0, stream>>>(feats_c, inp_w, inp_b,
                                                    h_c, nullptr, nullptr, H_, INCH_);
    // 2. ConvNeXt blocks
    for (int blk = 0; blk < 2; blk++){
      const float* dww = b_dw_w + blk*H_*9;     const float* dwb = b_dw_b + blk*H_;
      const float* lnw = b_ln_w + blk*H_;       const float* lnb = b_ln_b + blk*H_;
      const float* p1w = b_pw1_w + blk*HID_*H_; const float* p1b = b_pw1_b + blk*HID_;
      const float* gg  = b_grn_g + blk*HID_;    const float* gb  = b_grn_b + blk*HID_;
      const float* p2w = b_pw2_w + blk*H_*HID_; const float* p2b = b_pw2_b + blk*H_;
      dwconv_ln_kernel<<<(int)Mc, 192, 0, stream>>>(h_c, dww, dwb, lnw, lnb, yln_c);
      gemm64<1><<<dim3(gemm_mx, 3), 256, 0, stream>>>(yln_c, p1w, p1b,
                                                      y1_c, nullptr, nullptr, HID_, H_);
      grn_stats_kernel<<<Bc, 384, 0, stream>>>(y1_c, gg, scaleB);
      gemm64<2><<<dim3(gemm_mx, 2), 256, 0, stream>>>(y1_c, p2w, p2b,
                                                      h_c, scaleB, gb, H_, HID_);
    }
    // 3. output LN -> h_seq (reuse yln_c), save last-t rows
    out_ln_kernel<<<(int)Mc, 192, 0, stream>>>(h_c, out_ln_w, out_ln_b, yln_c, hlast, ch*Bc);
    // 4. Kalman projection + wide transcendental prep + FMA-only scan
    gemm64<0><<<dim3(gemm_mx, 1), 256, 0, stream>>>(yln_c, w_pad, b_pad,
                                                    rpraw, nullptr, nullptr, 64, H_);
    kalman_prep_kernel<<<(int)((Mc*32+255)/256), 256, 0, stream>>>(rpraw, rp_c, (int)Mc);
    kalman_scan_kernel<<<(Bc+3)/4, 64, 0, stream>>>(x_c, rp_c, xpost, ch*Bc, Bc);
  }
  // 5. GRU rollout (all batches, BPB per block, split-K)
  rollout_kernel<<<B_/BPB, RT_, 0, stream>>>(hlast, xpost, wT1, roll_in_b, wPack,
                                             gru_bih, gru_bhh, roll_ln_w, roll_ln_b,
                                             fc_rp_r_w, fc_rp_r_b, out);
  (void)in_sizes; (void)n_in; (void)out_size; (void)ws_size;
}

// Round 7
// 3342.369 us; speedup vs baseline: 1.9832x; 1.0605x over previous
//
#include <hip/hip_runtime.h>
#include <cstdint>
#include <cstddef>

#define B_    256
#define Q_    512
#define D_    32
#define H_    192
#define HID_  384
#define INCH_ 96
#define M_    (B_*Q_)    // 131072
#define WOUT_ 64
#define BPB   4          // batches per rollout block
#define RT_   384        // rollout threads (split-K 2-way over 192 outputs)
#define PI_F  3.14159265358979323846f

typedef unsigned int uint_t;

__device__ __forceinline__ float sigm(float x){ return 1.f/(1.f+expf(-x)); }
__device__ __forceinline__ float gelu_exact(float x){ return 0.5f*x*(1.f+erff(x*0.7071067811865475f)); }

// ---------------- features: [x, dy, ddy] ----------------
__global__ void feats_kernel(const float* __restrict__ x, float* __restrict__ feats, int nrows){
  int idx = blockIdx.x*256 + threadIdx.x;
  if (idx >= nrows*32) return;
  int d  = idx & 31;
  int bt = idx >> 5;
  int t  = bt & 511;
  const float* xr = x + (size_t)bt*D_;
  float xc  = xr[d];
  float xm1 = (t>0) ? xr[d - D_]   : 0.f;
  float xm2 = (t>1) ? xr[d - 2*D_] : 0.f;
  float dy   = (t>0) ? xc - xm1   : 0.f;
  float dym1 = (t>1) ? xm1 - xm2  : 0.f;
  float ddy  = (t>0) ? dy - dym1  : 0.f;
  float* fr = feats + (size_t)bt*INCH_;
  fr[d] = xc; fr[D_+d] = dy; fr[2*D_+d] = ddy;
}

// ---------------- 64x64x8 fp32 tiled GEMM, 4 blocks/CU ----------------
// MODE 0: out = acc+bias ; MODE 1: out = gelu(acc+bias) ; MODE 2: A affine, C += acc+bias
template<int MODE>
__global__ __launch_bounds__(256,4) void gemm_t64(
    const float* __restrict__ Af,
    const float* __restrict__ W,  const float* __restrict__ bias,
    float* __restrict__ Cf,
    const float* __restrict__ scale, const float* __restrict__ grnb,
    int N, int K)
{
  __shared__ float As[8][64];
  __shared__ float Bs[8][64];
  const int tid = threadIdx.x;
  const int bm = blockIdx.x*64, bn = blockIdx.y*64;
  const int tx = tid & 15, ty = tid >> 4;
  const int lrow = (tid & 127) >> 1, lk = (tid & 1)*4;
  const bool isA = tid < 128;
  const float* srow = (MODE==2) ? (scale + (size_t)(bm>>9)*HID_) : nullptr;

  float acc[4][4];
  #pragma unroll
  for (int i=0;i<4;i++)
    #pragma unroll
    for (int j=0;j<4;j++) acc[i][j]=0.f;

  const float* gsrc = isA ? (Af + (size_t)(bm+lrow)*K) : (W + (size_t)(bn+lrow)*K);

  for (int k0=0;k0<K;k0+=8){
    float4 v = *(const float4*)(gsrc + k0 + lk);
    if (MODE==2 && isA){
      int c = k0+lk;
      float4 sc = *(const float4*)(srow+c);
      float4 gb = *(const float4*)(grnb+c);
      v.x = v.x*sc.x+gb.x; v.y = v.y*sc.y+gb.y;
      v.z = v.z*sc.z+gb.z; v.w = v.w*sc.w+gb.w;
    }
    if (isA){
      As[lk+0][lrow]=v.x; As[lk+1][lrow]=v.y; As[lk+2][lrow]=v.z; As[lk+3][lrow]=v.w;
    } else {
      Bs[lk+0][lrow]=v.x; Bs[lk+1][lrow]=v.y; Bs[lk+2][lrow]=v.z; Bs[lk+3][lrow]=v.w;
    }
    __syncthreads();
    #pragma unroll
    for (int kk=0;kk<8;kk++){
      float4 a = *(const float4*)&As[kk][ty*4];
      float4 b = *(const float4*)&Bs[kk][tx*4];
      float ar[4] = {a.x,a.y,a.z,a.w};
      #pragma unroll
      for (int i=0;i<4;i++){
        acc[i][0] += ar[i]*b.x; acc[i][1] += ar[i]*b.y;
        acc[i][2] += ar[i]*b.z; acc[i][3] += ar[i]*b.w;
      }
    }
    __syncthreads();
  }

  const int o0 = bn + tx*4;
  float4 b0 = *(const float4*)(bias + o0);
  #pragma unroll
  for (int i=0;i<4;i++){
    int m = bm + ty*4 + i;
    if (MODE==0){
      float4 v; v.x=acc[i][0]+b0.x; v.y=acc[i][1]+b0.y; v.z=acc[i][2]+b0.z; v.w=acc[i][3]+b0.w;
      *(float4*)(Cf + (size_t)m*N + o0) = v;
    } else if (MODE==1){
      float4 v;
      v.x = gelu_exact(acc[i][0]+b0.x); v.y = gelu_exact(acc[i][1]+b0.y);
      v.z = gelu_exact(acc[i][2]+b0.z); v.w = gelu_exact(acc[i][3]+b0.w);
      *(float4*)(Cf + (size_t)m*N + o0) = v;
    } else {
      float4 old = *(const float4*)(Cf + (size_t)m*N + o0);
      float4 v; v.x=old.x+acc[i][0]+b0.x; v.y=old.y+acc[i][1]+b0.y;
      v.z=old.z+acc[i][2]+b0.z; v.w=old.w+acc[i][3]+b0.w;
      *(float4*)(Cf + (size_t)m*N + o0) = v;
    }
  }
}

// ---------------- depthwise conv (k=9, edge pad) + LN, 4 timesteps per block ----------------
__global__ __launch_bounds__(192) void dwconv_ln4(
  const float* __restrict__ h, const float* __restrict__ dww, const float* __restrict__ dwb,
  const float* __restrict__ lnw, const float* __restrict__ lnb, float* __restrict__ yln)
{
  __shared__ float sh[12][192];
  __shared__ float rs_[192], rq_[192], st[2];
  const int c  = threadIdx.x;
  const int t0 = (blockIdx.x & 127) * 4;
  const size_t base = (size_t)(blockIdx.x >> 7) * Q_ * H_;
  #pragma unroll
  for (int r=0;r<12;r++){
    int tt = t0 - 4 + r; tt = tt<0?0:(tt>511?511:tt);
    sh[r][c] = h[base + (size_t)tt*H_ + c];
  }
  float w[9];
  #pragma unroll
  for (int k=0;k<9;k++) w[k] = dww[c*9+k];
  const float dbias = dwb[c], lw = lnw[c], lb = lnb[c];
  __syncthreads();
  for (int i=0;i<4;i++){
    float acc = dbias;
    #pragma unroll
    for (int k=0;k<9;k++) acc += w[k]*sh[i+k][c];
    rs_[c]=acc; rq_[c]=acc*acc;
    __syncthreads();
    if (c < 64){
      float s = rs_[c]+rs_[c+64]+rs_[c+128];
      float q = rq_[c]+rq_[c+64]+rq_[c+128];
      #pragma unroll
      for (int off=32; off>0; off>>=1){ s += __shfl_down(s,off); q += __shfl_down(q,off); }
      if (c==0){ st[0]=s; st[1]=q; }
    }
    __syncthreads();
    float mean = st[0]*(1.f/H_);
    float var  = st[1]*(1.f/H_) - mean*mean;
    float r = rsqrtf(var + 1e-5f);
    yln[base + (size_t)(t0+i)*H_ + c] = (acc-mean)*r*lw + lb;
  }
}

// ---------------- output LayerNorm (+ save last-timestep row) ----------------
__global__ __launch_bounds__(192) void out_ln_kernel(
  const float* __restrict__ h, const float* __restrict__ lnw, const float* __restrict__ lnb,
  float* __restrict__ o, float* __restrict__ hlast, int b0)
{
  __shared__ float rs_[192], rq_[192], st[2];
  const int c  = threadIdx.x;
  const int bt = blockIdx.x;
  float v = h[(size_t)bt*H_ + c];
  rs_[c]=v; rq_[c]=v*v;
  __syncthreads();
  if (c < 64){
    float s = rs_[c]+rs_[c+64]+rs_[c+128];
    float q = rq_[c]+rq_[c+64]+rq_[c+128];
    #pragma unroll
    for (int off=32; off>0; off>>=1){ s += __shfl_down(s,off); q += __shfl_down(q,off); }
    if (c==0){ st[0]=s; st[1]=q; }
  }
  __syncthreads();
  float mean = st[0]*(1.f/H_);
  float var  = st[1]*(1.f/H_) - mean*mean;
  float r = rsqrtf(var + 1e-5f);
  float res = (v-mean)*r*lnw[c] + lnb[c];
  o[(size_t)bt*H_ + c] = res;
  if ((bt & 511) == 511) hlast[(size_t)(b0 + (bt>>9))*H_ + c] = res;
}

// ---------------- GRN stats ----------------
__global__ __launch_bounds__(384) void grn_stats_kernel(
  const float* __restrict__ y1, const float* __restrict__ grn_g, float* __restrict__ scale)
{
  __shared__ float r[384];
  const int c = threadIdx.x;
  const int b = blockIdx.x;
  const float* p = y1 + (size_t)b*Q_*HID_ + c;
  float s = 0.f;
  #pragma unroll 8
  for (int t=0;t<Q_;t++){ float v = p[(size_t)t*HID_]; s += v*v; }
  float gx = sqrtf(s);
  r[c] = gx;
  __syncthreads();
  if (c < 64){
    float v = r[c]+r[c+64]+r[c+128]+r[c+192]+r[c+256]+r[c+320];
    #pragma unroll
    for (int off=32; off>0; off>>=1) v += __shfl_down(v,off);
    if (c==0) r[0]=v;
  }
  __syncthreads();
  float mean = r[0]*(1.f/HID_);
  scale[(size_t)b*HID_ + c] = 1.f + grn_g[c]*gx/(mean + 1e-6f);
}

// ---------------- pack fc_rp / fc_gain into padded (64,192) W ----------------
__global__ void pack_w_kernel(const float* __restrict__ frw, const float* __restrict__ frb,
                              const float* __restrict__ fgw, const float* __restrict__ fgb,
                              float* __restrict__ w_pad, float* __restrict__ b_pad)
{
  int idx = blockIdx.x*256 + threadIdx.x;
  if (idx >= 64*192) return;
  int o = idx / 192, k = idx % 192;
  float v = 0.f;
  if (o < 2) v = frw[o*192+k]; else if (o < 34) v = fgw[(o-2)*192+k];
  w_pad[idx] = v;
  if (k == 0){
    float bv = 0.f;
    if (o < 2) bv = frb[o]; else if (o < 34) bv = fgb[o-2];
    b_pad[o] = bv;
  }
}

// ---------------- wide Kalman prep ----------------
__global__ void kalman_prep_kernel(const float* __restrict__ raw, float* __restrict__ rp, int nrows){
  int idx = blockIdx.x*256 + threadIdx.x;
  if (idx >= nrows*32) return;
  int d  = idx & 31;
  int bt = idx >> 5;
  const float* r = raw + (size_t)bt*64;
  float* o = rp + (size_t)bt*34;
  o[2+d] = sigm(r[2+d]);
  if (d==0){
    float rho = 1.25f*sigm(r[0]);
    float phi = PI_F * tanhf(r[1]);
    o[0] = rho*cosf(phi);
    o[1] = rho*sinf(phi);
  }
}

// ---------------- sequential Kalman scan (FMA-only) ----------------
__global__ __launch_bounds__(64) void kalman_scan_kernel(
  const float* __restrict__ x_c, const float* __restrict__ rp, float* __restrict__ xpost,
  int b0, int Bc)
{
  const int lane = threadIdx.x;
  const int bl = blockIdx.x*4 + (lane>>4);
  if (bl >= Bc) return;
  const int m = lane & 15;
  const float* xb  = x_c + (size_t)bl*Q_*D_;
  const float* rpb = rp  + (size_t)bl*Q_*34;
  float re = xb[m], im = xb[16+m];
  for (int t=0;t<Q_;t++){
    const float* r = rpb + (size_t)t*34;
    float rc = r[0], rs = r[1];
    float g0 = r[2+m], g1 = r[18+m];
    float y0 = xb[(size_t)t*D_ + m], y1v = xb[(size_t)t*D_ + 16 + m];
    float pr  = rc*re - rs*im;
    float pim = rs*re + rc*im;
    re = pr  + g0*(y0  - pr);
    im = pim + g1*(y1v - pim);
  }
  xpost[(b0+bl)*D_ + m] = re;
  xpost[(b0+bl)*D_ + 16 + m] = im;
}

// ---------------- rollout weight prep: wT1[k][o] + packed [k][o][8] gate block ----------------
__global__ void prep_rollout_kernel(const float* __restrict__ riw, const float* __restrict__ wih,
                                    const float* __restrict__ whh,
                                    float* __restrict__ wT1, float* __restrict__ wPack)
{
  int idx = blockIdx.x*256 + threadIdx.x;
  if (idx < 224*192){
    int o = idx % 192, k = idx / 192;
    wT1[idx] = riw[o*224 + k];
    return;
  }
  idx -= 224*192;
  if (idx < 192*192){
    int o = idx % 192, k = idx / 192;
    float* w = wPack + ((size_t)k*192 + o)*8;
    w[0] = wih[(0*192+o)*192 + k];
    w[1] = wih[(1*192+o)*192 + k];
    w[2] = wih[(2*192+o)*192 + k];
    w[3] = whh[(0*192+o)*192 + k];
    w[4] = whh[(1*192+o)*192 + k];
    w[5] = whh[(2*192+o)*192 + k];
    w[6] = 0.f; w[7] = 0.f;
  }
}

// ---------------- GRU rollout: BPB batches/block, 384 threads split-K 2-way (R5 passing version) ----------------
__global__ __launch_bounds__(RT_) void rollout_kernel(
  const float* __restrict__ hlast, const float* __restrict__ xpost,
  const float* __restrict__ wT1,  const float* __restrict__ rib_,
  const float* __restrict__ wPack,
  const float* __restrict__ bih,  const float* __restrict__ bhh,
  const float* __restrict__ lnw,  const float* __restrict__ lnb,
  const float* __restrict__ frw,  const float* __restrict__ frb,
  float* __restrict__ out)
{
  const int tid  = threadIdx.x;
  const int half = (tid >= 192) ? 1 : 0;   // wave-aligned split (192 = 3 waves)
  const int o    = tid - half*192;
  const int bb   = blockIdx.x*BPB;
  __shared__ float h[BPB][192], x[BPB][192], c[BPB][32];
  __shared__ float pA[192][BPB+1];
  __shared__ float pB[192][25];
  __shared__ float red1[BPB][192], red2[BPB][192];
  __shared__ float stL[BPB][2], stR[BPB][2];

  if (half==0){
    #pragma unroll
    for (int j=0;j<BPB;j++) h[j][o] = hlast[(size_t)(bb+j)*H_ + o];
  }
  if (tid < 32){
    #pragma unroll
    for (int j=0;j<BPB;j++) c[j][tid] = xpost[(bb+j)*D_ + tid];
  }
  const float w_ln = lnw[o], b_ln = lnb[o];
  const float w_r0 = frw[o], w_r1 = frw[192+o];
  const float fb0 = frb[0], fb1 = frb[1];
  const float bi0 = bih[o], bi1 = bih[192+o], bi2 = bih[384+o];
  const float bh0 = bhh[o], bh1 = bhh[192+o], bh2 = bhh[384+o];
  const float rib = rib_[o];
  __syncthreads();

  for (int s=0; s<WOUT_; s++){
    // ---- phase A: x = tanh(W1 @ [h; c] + b1), K split 0..111 / 112..223 ----
    float a[BPB];
    if (half==0){
      #pragma unroll
      for (int j=0;j<BPB;j++) a[j] = rib;
      #pragma unroll 4
      for (int k=0;k<112;k++){
        float w = wT1[k*192+o];
        #pragma unroll
        for (int j=0;j<BPB;j++) a[j] += w*h[j][k];
      }
    } else {
      #pragma unroll
      for (int j=0;j<BPB;j++) a[j] = 0.f;
      #pragma unroll 4
      for (int k=112;k<192;k++){
        float w = wT1[k*192+o];
        #pragma unroll
        for (int j=0;j<BPB;j++) a[j] += w*h[j][k];
      }
      #pragma unroll
      for (int k=0;k<32;k++){
        float w = wT1[(192+k)*192+o];
        #pragma unroll
        for (int j=0;j<BPB;j++) a[j] += w*c[j][k];
      }
      #pragma unroll
      for (int j=0;j<BPB;j++) pA[o][j] = a[j];
    }
    __syncthreads();
    if (half==0){
      #pragma unroll
      for (int j=0;j<BPB;j++) x[j][o] = tanhf(a[j] + pA[o][j]);
    }
    __syncthreads();

    // ---- phase B: 6 gates, K split 0..95 / 96..191 ----
    float p0[BPB], p1[BPB], p2[BPB], q0[BPB], q1[BPB], q2[BPB];
    #pragma unroll
    for (int j=0;j<BPB;j++){
      p0[j] = half ? 0.f : bi0; p1[j] = half ? 0.f : bi1; p2[j] = half ? 0.f : bi2;
      q0[j] = half ? 0.f : bh0; q1[j] = half ? 0.f : bh1; q2[j] = half ? 0.f : bh2;
    }
    const int kb = half*96;
    #pragma unroll 2
    for (int k=kb;k<kb+96;k++){
      const float4* wp = (const float4*)(wPack + ((size_t)k*192 + o)*8);
      float4 wA = wp[0];
      float4 wB = wp[1];
      #pragma unroll
      for (int j=0;j<BPB;j++){
        float xv = x[j][k], hv = h[j][k];
        p0[j] += wA.x*xv; p1[j] += wA.y*xv; p2[j] += wA.z*xv;
        q0[j] += wA.w*hv; q1[j] += wB.x*hv; q2[j] += wB.y*hv;
      }
    }
    if (half==1){
      #pragma unroll
      for (int j=0;j<BPB;j++){
        pB[o][j*6+0]=p0[j]; pB[o][j*6+1]=p1[j]; pB[o][j*6+2]=p2[j];
        pB[o][j*6+3]=q0[j]; pB[o][j*6+4]=q1[j]; pB[o][j*6+5]=q2[j];
      }
    }
    __syncthreads();
    float pre[BPB];
    if (half==0){
      #pragma unroll
      for (int j=0;j<BPB;j++){
        float P0=p0[j]+pB[o][j*6+0], P1=p1[j]+pB[o][j*6+1], P2=p2[j]+pB[o][j*6+2];
        float Q0=q0[j]+pB[o][j*6+3], Q1=q1[j]+pB[o][j*6+4], Q2=q2[j]+pB[o][j*6+5];
        float rg = sigm(P0+Q0), z = sigm(P1+Q1);
        float n  = tanhf(P2 + rg*Q2);
        pre[j] = (1.f - z)*n + z*h[j][o];
        red1[j][o] = pre[j]; red2[j][o] = pre[j]*pre[j];
      }
    }
    __syncthreads();
    if (tid < 64){
      #pragma unroll
      for (int j=0;j<BPB;j++){
        float s0 = red1[j][tid]+red1[j][tid+64]+red1[j][tid+128];
        float q0r= red2[j][tid]+red2[j][tid+64]+red2[j][tid+128];
        #pragma unroll
        for (int off=32; off>0; off>>=1){ s0 += __shfl_down(s0,off); q0r += __shfl_down(q0r,off); }
        if (tid==0){ stL[j][0]=s0; stL[j][1]=q0r; }
      }
    }
    __syncthreads();
    if (half==0){
      const float inv = 1.f/192.f;
      #pragma unroll
      for (int j=0;j<BPB;j++){
        float mu = stL[j][0]*inv, var = stL[j][1]*inv - mu*mu;
        float hn = (pre[j]-mu)*rsqrtf(var+1e-5f)*w_ln + b_ln;
        h[j][o] = hn;
        red1[j][o] = hn*w_r0; red2[j][o] = hn*w_r1;
      }
    }
    __syncthreads();
    if (tid < 64){
      #pragma unroll
      for (int j=0;j<BPB;j++){
        float s0 = red1[j][tid]+red1[j][tid+64]+red1[j][tid+128];
        float q0r= red2[j][tid]+red2[j][tid+64]+red2[j][tid+128];
        #pragma unroll
        for (int off=32; off>0; off>>=1){ s0 += __shfl_down(s0,off); q0r += __shfl_down(q0r,off); }
        if (tid==0){ stR[j][0]=s0; stR[j][1]=q0r; }
      }
    }
    __syncthreads();
    if (tid < 16){
      #pragma unroll
      for (int j=0;j<BPB;j++){
        float rho = 1.25f*sigm(stR[j][0]+fb0);
        float phi = PI_F*tanhf(stR[j][1]+fb1);
        float rc = rho*cosf(phi), rs = rho*sinf(phi);
        float re = c[j][tid], im = c[j][tid+16];
        float nre = rc*re - rs*im;
        float nim = rs*re + rc*im;
        c[j][tid] = nre; c[j][tid+16] = nim;
        float* ob = out + ((size_t)(bb+j)*WOUT_ + s)*D_;
        ob[tid] = nre; ob[tid+16] = nim;
      }
    }
    __syncthreads();
  }
}

// ---------------- host launch ----------------
extern "C" void kernel_launch(void* const* d_in, const int* in_sizes, int n_in,
                              void* d_out, int out_size, void* d_ws, size_t ws_size,
                              hipStream_t stream)
{
  const float* x_in     = (const float*)d_in[0];
  const float* inp_w    = (const float*)d_in[1];
  const float* inp_b    = (const float*)d_in[2];
  const float* b_dw_w   = (const float*)d_in[3];
  const float* b_dw_b   = (const float*)d_in[4];
  const float* b_ln_w   = (const float*)d_in[5];
  const float* b_ln_b   = (const float*)d_in[6];
  const float* b_pw1_w  = (const float*)d_in[7];
  const float* b_pw1_b  = (const float*)d_in[8];
  const float* b_grn_g  = (const float*)d_in[9];
  const float* b_grn_b  = (const float*)d_in[10];
  const float* b_pw2_w  = (const float*)d_in[11];
  const float* b_pw2_b  = (const float*)d_in[12];
  const float* out_ln_w = (const float*)d_in[13];
  const float* out_ln_b = (const float*)d_in[14];
  const float* fc_rp_w  = (const float*)d_in[15];
  const float* fc_rp_b  = (const float*)d_in[16];
  const float* fc_gain_w= (const float*)d_in[17];
  const float* fc_gain_b= (const float*)d_in[18];
  const float* roll_in_w= (const float*)d_in[19];
  const float* roll_in_b= (const float*)d_in[20];
  const float* gru_wih  = (const float*)d_in[21];
  const float* gru_whh  = (const float*)d_in[22];
  const float* gru_bih  = (const float*)d_in[23];
  const float* gru_bhh  = (const float*)d_in[24];
  const float* roll_ln_w= (const float*)d_in[25];
  const float* roll_ln_b= (const float*)d_in[26];
  const float* fc_rp_r_w= (const float*)d_in[27];
  const float* fc_rp_r_b= (const float*)d_in[28];
  float* out = (float*)d_out;

  // ---- adaptive chunking ----
  // per-row floats: h(192) + yln(192) + mid(384; feats/y1, then rpraw(64)+rp(34)) = 768
  // fixed tail (R5 layout): scaleB 98304 + w_pad 12288 + b_pad 64 + xpost 8192 + hlast 49152
  //           + wT1 43008 + wPack 294912 = 505920 ; + margin
  const size_t SMAL_FLOATS = 505920 + 4096;
  size_t ws_floats = ws_size / 4;
  int nchunk = 256;
  const int cand[9] = {1,2,4,8,16,32,64,128,256};
  for (int ci=0; ci<9; ci++){
    size_t Mc_try = (size_t)M_ / cand[ci];
    if (Mc_try*768 + SMAL_FLOATS <= ws_floats){ nchunk = cand[ci]; break; }
  }
  const int    Bc = B_ / nchunk;
  const size_t Mc = (size_t)Bc * Q_;

  float* ws    = (float*)d_ws;
  float* h_c   = ws;
  float* yln_c = h_c   + Mc*192;
  float* mid_c = yln_c + Mc*192;
  float* smal  = mid_c + Mc*384;

  float* feats_c = mid_c;
  float* y1_c    = mid_c;
  float* rpraw   = mid_c;                // Mc*64 (y1 dead by then)
  float* rp_c    = mid_c + Mc*64;        // Mc*34

  float* scaleB = smal;                  // Bc*384 (reserve 98304)
  float* w_pad  = smal + 98304;          // 64*192
  float* b_pad  = w_pad + 12288;         // 64
  float* xpost  = b_pad + 64;            // B_*32
  float* hlast  = xpost + 8192;          // B_*192
  float* wT1    = hlast + 49152;         // 224*192
  float* wPack  = wT1 + 43008;           // 192*192*8

  // one-time weight prep
  pack_w_kernel<<<(64*192+255)/256, 256, 0, stream>>>(fc_rp_w, fc_rp_b, fc_gain_w, fc_gain_b, w_pad, b_pad);
  prep_rollout_kernel<<<(224*192+192*192+255)/256, 256, 0, stream>>>(roll_in_w, gru_wih, gru_whh, wT1, wPack);

  const int gmx = (int)(Mc/64);
  for (int ch=0; ch<nchunk; ch++){
    const float* x_c = x_in + (size_t)ch*Mc*D_;
    // 1. features + input projection
    feats_kernel<<<(int)((Mc*32+255)/256), 256, 0, stream>>>(x_c, feats_c, (int)Mc);
    gemm_t64<0><<<dim3(gmx, 3), 256, 0, stream>>>(feats_c, inp_w, inp_b,
                                                  h_c, nullptr, nullptr, H_, INCH_);
    // 2. ConvNeXt blocks
    for (int blk = 0; blk < 2; blk++){
      const float* dww = b_dw_w + blk*H_*9;     const float* dwb = b_dw_b + blk*H_;
      const float* lnw = b_ln_w + blk*H_;       const float* lnb = b_ln_b + blk*H_;
      const float* p1w = b_pw1_w + blk*HID_*H_; const float* p1b = b_pw1_b + blk*HID_;
      const float* gg  = b_grn_g + blk*HID_;    const float* gb  = b_grn_b + blk*HID_;
      const float* p2w = b_pw2_w + blk*H_*HID_; const float* p2b = b_pw2_b + blk*H_;
      dwconv_ln4<<<(int)(Mc/4), 192, 0, stream>>>(h_c, dww, dwb, lnw, lnb, yln_c);
      gemm_t64<1><<<dim3(gmx, 6), 256, 0, stream>>>(yln_c, p1w, p1b,
                                                    y1_c, nullptr, nullptr, HID_, H_);
      grn_stats_kernel<<<Bc, 384, 0, stream>>>(y1_c, gg, scaleB);
      gemm_t64<2><<<dim3(gmx, 3), 256, 0, stream>>>(y1_c, p2w, p2b,
                                                    h_c, scaleB, gb, H_, HID_);
    }
    // 3. output LN -> h_seq, save last-t rows
    out_ln_kernel<<<(int)Mc, 192, 0, stream>>>(h_c, out_ln_w, out_ln_b, yln_c, hlast, ch*Bc);
    // 4. Kalman projection + wide transcendental prep + FMA-only scan
    gemm_t64<0><<<dim3(gmx, 1), 256, 0, stream>>>(yln_c, w_pad, b_pad,
                                                  rpraw, nullptr, nullptr, 64, H_);
    kalman_prep_kernel<<<(int)((Mc*32+255)/256), 256, 0, stream>>>(rpraw, rp_c, (int)Mc);
    kalman_scan_kernel<<<(Bc+3)/4, 64, 0, stream>>>(x_c, rp_c, xpost, ch*Bc, Bc);
  }
  // 5. GRU rollout (R5 passing version: 64 blocks, BPB=4, split-K)
  rollout_kernel<<<B_/BPB, RT_, 0, stream>>>(hlast, xpost, wT1, roll_in_b, wPack,
                                             gru_bih, gru_bhh, roll_ln_w, roll_ln_b,
                                             fc_rp_r_w, fc_rp_r_b, out);
  (void)in_sizes; (void)n_in; (void)out_size; (void)ws_size;
}